// Round 12
// baseline (308.147 us; speedup 1.0000x reference)
//
#include <hip/hip_runtime.h>
#include <hip/hip_bf16.h>
#include <math.h>

// Problem constants
#define MM 2048        // B*W flattened rows
#define BATCH 2
#define SEQ 1024
#define DMODEL 512
#define DINNER 1024
#define DSTATE 16
#define DTRANK 32
#define DFF 2048

// Chunked-scan constants
#define NCHUNK 16
#define CHUNK 64
#define GTOT 65536          // 2 dirs * BATCH * DINNER * DSTATE

typedef short bf16x8 __attribute__((ext_vector_type(8)));
typedef float floatx4 __attribute__((ext_vector_type(4)));
typedef unsigned short ushort8v __attribute__((ext_vector_type(8)));
typedef unsigned short ushort4v __attribute__((ext_vector_type(4)));

__device__ __forceinline__ unsigned short f2bf(float f) {
    union { float f; unsigned u; } v; v.f = f;
    unsigned r = v.u + 0x7FFF + ((v.u >> 16) & 1);
    return (unsigned short)(r >> 16);
}
__device__ __forceinline__ float bf2f(unsigned short u) {
    union { unsigned u; float f; } v; v.u = ((unsigned)u) << 16; return v.f;
}

// Sum across each 4-lane quad via DPP quad_perm adds (VALU-only).
__device__ __forceinline__ float quadsum4(float x) {
    union { float f; int i; } a, b;
    a.f = x;
    b.i = __builtin_amdgcn_update_dpp(0, a.i, 0xB1, 0xF, 0xF, false); a.f += b.f; // [1,0,3,2]
    b.i = __builtin_amdgcn_update_dpp(0, a.i, 0x4E, 0xF, 0xF, false); a.f += b.f; // [2,3,0,1]
    return a.f;
}

#define GLOAD_LDS16(gp, lp) __builtin_amdgcn_global_load_lds( \
    (const __attribute__((address_space(1))) unsigned int*)(gp), \
    (__attribute__((address_space(3))) unsigned int*)(lp), 16, 0, 0)

// NOTE: single-buffered barrier-stage-barrier K-loops only. The LDS
// double-buffer variant RACES on this compiler (round-9 post-timing
// divergence): waitcnt insertion ties the LDS-DMA drain to aliasing
// ds_reads, which never alias the freshest DMA in a dbuf loop -> missing
// vmcnt wait across the loop backedge. BK=64 stages both 32-k halves before
// ONE barrier (disjoint LDS, all pre-barrier) — safe, and measured-neutral
// vs BK=32 (round 11), kept for fewer barriers.

// ---------------------------------------------------------------------------
// Batched direct bf16 MFMA GEMM: C[z][M,N] = epi(A[z] @ B[z]^T + bias)
// 128x128 tile, BK=64. Conflict-free LDS. K % 64 == 0.
// ---------------------------------------------------------------------------
template<int EPI, int OUTBF16>
__global__ __launch_bounds__(256) void gemm_mfma_batch(
    int M, int N, int K,
    const unsigned short* __restrict__ A0, const unsigned short* __restrict__ A1, int lda,
    const unsigned short* __restrict__ B0, const unsigned short* __restrict__ B1, int ldb,
    const float* __restrict__ bias,
    void* __restrict__ C0, void* __restrict__ C1, int ldc)
{
    __shared__ unsigned short As[2][128 * 32];
    __shared__ unsigned short Bs[2][128 * 32];
    const int z = blockIdx.z;
    const unsigned short* A = z ? A1 : A0;
    const unsigned short* B = z ? B1 : B0;
    void* Cout = z ? C1 : C0;
    const int tid  = threadIdx.x;
    const int wave = tid >> 6;
    const int lane = tid & 63;
    const int bm = blockIdx.y * 128;
    const int bn = blockIdx.x * 128;

    const int strow = lane & 15;
    const int stkc  = lane >> 4;
    const int wr = wave >> 1, wc = wave & 1;
    const int frow = lane & 15;
    const int fkc  = lane >> 4;

    floatx4 acc[4][4];
    #pragma unroll
    for (int i = 0; i < 4; ++i)
        #pragma unroll
        for (int j = 0; j < 4; ++j)
            acc[i][j] = (floatx4){0.f, 0.f, 0.f, 0.f};

    for (int k0 = 0; k0 < K; k0 += 64) {
        __syncthreads();
        #pragma unroll
        for (int hh = 0; hh < 2; ++hh) {
            #pragma unroll
            for (int q = 0; q < 2; ++q) {
                int g = wave * 2 + q;
                GLOAD_LDS16(A + (size_t)(bm + g * 16 + strow) * lda + k0 + hh * 32 + stkc * 8,
                            As[hh] + g * 512);
            }
            #pragma unroll
            for (int q = 0; q < 2; ++q) {
                int g = wave * 2 + q;
                GLOAD_LDS16(B + (size_t)(bn + g * 16 + strow) * ldb + k0 + hh * 32 + stkc * 8,
                            Bs[hh] + g * 512);
            }
        }
        __syncthreads();

        #pragma unroll
        for (int hh = 0; hh < 2; ++hh) {
            bf16x8 af[4], bfr[4];
            #pragma unroll
            for (int i = 0; i < 4; ++i)
                af[i] = *(const bf16x8*)(As[hh] + (wr * 4 + i) * 512 + fkc * 128 + frow * 8);
            #pragma unroll
            for (int j = 0; j < 4; ++j)
                bfr[j] = *(const bf16x8*)(Bs[hh] + (wc * 4 + j) * 512 + fkc * 128 + frow * 8);
            #pragma unroll
            for (int i = 0; i < 4; ++i)
                #pragma unroll
                for (int j = 0; j < 4; ++j)
                    acc[i][j] = __builtin_amdgcn_mfma_f32_16x16x32_bf16(
                        af[i], bfr[j], acc[i][j], 0, 0, 0);
        }
    }

    const int orow0 = bm + wr * 64 + (lane >> 4) * 4;
    const int ocol0 = bn + wc * 64 + (lane & 15);
    #pragma unroll
    for (int j = 0; j < 4; ++j) {
        const int col = ocol0 + j * 16;
        const float bv = bias ? bias[col] : 0.f;
        #pragma unroll
        for (int i = 0; i < 4; ++i) {
            #pragma unroll
            for (int r = 0; r < 4; ++r) {
                int row = orow0 + i * 16 + r;
                float t = acc[i][j][r] + bv;
                if (EPI == 1) t = fmaxf(t, 0.f);
                if (OUTBF16)
                    ((unsigned short*)Cout)[(size_t)row * ldc + col] = f2bf(t);
                else
                    ((float*)Cout)[(size_t)row * ldc + col] = t;
            }
        }
    }
}

// ---------------------------------------------------------------------------
// In-proj GEMM (BK=64): writes bf16 x-half / z-half buffers (each [M][1024]).
// A shared across dirs; blockIdx.z = dir. M=MM, N=2048, K=512.
// ---------------------------------------------------------------------------
__global__ __launch_bounds__(256) void gemm_inproj_kernel(
    const unsigned short* __restrict__ A,
    const unsigned short* __restrict__ B0, const unsigned short* __restrict__ B1,
    unsigned short* __restrict__ Cx0, unsigned short* __restrict__ Cz0,
    unsigned short* __restrict__ Cx1, unsigned short* __restrict__ Cz1)
{
    __shared__ unsigned short As[2][128 * 32];
    __shared__ unsigned short Bs[2][128 * 32];
    const int z = blockIdx.z;
    const unsigned short* B = z ? B1 : B0;
    const int tid  = threadIdx.x;
    const int wave = tid >> 6;
    const int lane = tid & 63;
    const int bm = blockIdx.y * 128;
    const int bn = blockIdx.x * 128;

    const int strow = lane & 15;
    const int stkc  = lane >> 4;
    const int wr = wave >> 1, wc = wave & 1;
    const int frow = lane & 15;
    const int fkc  = lane >> 4;

    floatx4 acc[4][4];
    #pragma unroll
    for (int i = 0; i < 4; ++i)
        #pragma unroll
        for (int j = 0; j < 4; ++j)
            acc[i][j] = (floatx4){0.f, 0.f, 0.f, 0.f};

    for (int k0 = 0; k0 < DMODEL; k0 += 64) {
        __syncthreads();
        #pragma unroll
        for (int hh = 0; hh < 2; ++hh) {
            #pragma unroll
            for (int q = 0; q < 2; ++q) {
                int g = wave * 2 + q;
                GLOAD_LDS16(A + (size_t)(bm + g * 16 + strow) * DMODEL + k0 + hh * 32 + stkc * 8,
                            As[hh] + g * 512);
            }
            #pragma unroll
            for (int q = 0; q < 2; ++q) {
                int g = wave * 2 + q;
                GLOAD_LDS16(B + (size_t)(bn + g * 16 + strow) * DMODEL + k0 + hh * 32 + stkc * 8,
                            Bs[hh] + g * 512);
            }
        }
        __syncthreads();

        #pragma unroll
        for (int hh = 0; hh < 2; ++hh) {
            bf16x8 af[4], bfr[4];
            #pragma unroll
            for (int i = 0; i < 4; ++i)
                af[i] = *(const bf16x8*)(As[hh] + (wr * 4 + i) * 512 + fkc * 128 + frow * 8);
            #pragma unroll
            for (int j = 0; j < 4; ++j)
                bfr[j] = *(const bf16x8*)(Bs[hh] + (wc * 4 + j) * 512 + fkc * 128 + frow * 8);
            #pragma unroll
            for (int i = 0; i < 4; ++i)
                #pragma unroll
                for (int j = 0; j < 4; ++j)
                    acc[i][j] = __builtin_amdgcn_mfma_f32_16x16x32_bf16(
                        af[i], bfr[j], acc[i][j], 0, 0, 0);
        }
    }

    const int zh = bn >= DINNER;
    unsigned short* C = z ? (zh ? Cz1 : Cx1) : (zh ? Cz0 : Cx0);
    const int cb = zh ? DINNER : 0;
    const int orow0 = bm + wr * 64 + (lane >> 4) * 4;
    const int ocol0 = bn + wc * 64 + (lane & 15) - cb;
    #pragma unroll
    for (int j = 0; j < 4; ++j) {
        const int col = ocol0 + j * 16;
        #pragma unroll
        for (int i = 0; i < 4; ++i)
            #pragma unroll
            for (int r = 0; r < 4; ++r)
                C[(size_t)(orow0 + i * 16 + r) * DINNER + col] = f2bf(acc[i][j][r]);
    }
}

// ---------------------------------------------------------------------------
// Split-K batched MFMA GEMM (BK=64) -> fp32 partials part[z][M*ldc].
// z = dir*NSPLIT + sp. (K/NSPLIT) % 64 == 0.
// ---------------------------------------------------------------------------
template<int NSPLIT>
__global__ __launch_bounds__(256) void gemm_mfma_splitk(
    int M, int N, int K,
    const unsigned short* __restrict__ A0, const unsigned short* __restrict__ A1, int lda,
    const unsigned short* __restrict__ B0, const unsigned short* __restrict__ B1, int ldb,
    float* __restrict__ part, int ldc)
{
    __shared__ unsigned short As[2][128 * 32];
    __shared__ unsigned short Bs[2][128 * 32];
    const int z = blockIdx.z;
    const int dir = z / NSPLIT, sp = z % NSPLIT;
    const unsigned short* A = dir ? A1 : A0;
    const unsigned short* B = dir ? B1 : B0;
    float* Cp = part + (size_t)z * M * ldc;
    const int kbeg = sp * (K / NSPLIT);
    const int kend = kbeg + (K / NSPLIT);
    const int tid  = threadIdx.x;
    const int wave = tid >> 6;
    const int lane = tid & 63;
    const int bm = blockIdx.y * 128;
    const int bn = blockIdx.x * 128;

    const int strow = lane & 15;
    const int stkc  = lane >> 4;
    const int wr = wave >> 1, wc = wave & 1;
    const int frow = lane & 15;
    const int fkc  = lane >> 4;

    floatx4 acc[4][4];
    #pragma unroll
    for (int i = 0; i < 4; ++i)
        #pragma unroll
        for (int j = 0; j < 4; ++j)
            acc[i][j] = (floatx4){0.f, 0.f, 0.f, 0.f};

    for (int k0 = kbeg; k0 < kend; k0 += 64) {
        __syncthreads();
        #pragma unroll
        for (int hh = 0; hh < 2; ++hh) {
            #pragma unroll
            for (int q = 0; q < 2; ++q) {
                int g = wave * 2 + q;
                GLOAD_LDS16(A + (size_t)(bm + g * 16 + strow) * lda + k0 + hh * 32 + stkc * 8,
                            As[hh] + g * 512);
            }
            #pragma unroll
            for (int q = 0; q < 2; ++q) {
                int g = wave * 2 + q;
                GLOAD_LDS16(B + (size_t)(bn + g * 16 + strow) * ldb + k0 + hh * 32 + stkc * 8,
                            Bs[hh] + g * 512);
            }
        }
        __syncthreads();

        #pragma unroll
        for (int hh = 0; hh < 2; ++hh) {
            bf16x8 af[4], bfr[4];
            #pragma unroll
            for (int i = 0; i < 4; ++i)
                af[i] = *(const bf16x8*)(As[hh] + (wr * 4 + i) * 512 + fkc * 128 + frow * 8);
            #pragma unroll
            for (int j = 0; j < 4; ++j)
                bfr[j] = *(const bf16x8*)(Bs[hh] + (wc * 4 + j) * 512 + fkc * 128 + frow * 8);
            #pragma unroll
            for (int i = 0; i < 4; ++i)
                #pragma unroll
                for (int j = 0; j < 4; ++j)
                    acc[i][j] = __builtin_amdgcn_mfma_f32_16x16x32_bf16(
                        af[i], bfr[j], acc[i][j], 0, 0, 0);
        }
    }

    const int orow0 = bm + wr * 64 + (lane >> 4) * 4;
    const int ocol0 = bn + wc * 64 + (lane & 15);
    #pragma unroll
    for (int j = 0; j < 4; ++j) {
        const int col = ocol0 + j * 16;
        #pragma unroll
        for (int i = 0; i < 4; ++i)
            #pragma unroll
            for (int r = 0; r < 4; ++r)
                Cp[(size_t)(orow0 + i * 16 + r) * ldc + col] = acc[i][j][r];
    }
}

// ---------------------------------------------------------------------------
// xproj split-K MFMA (BK=64): tile 128(m) x 64(n), K slice 256.
// blockIdx.y = dir*4 + sp.
// ---------------------------------------------------------------------------
__global__ __launch_bounds__(256) void xproj_splitk_kernel(
    const unsigned short* __restrict__ A_f, const unsigned short* __restrict__ A_b,
    const unsigned short* __restrict__ Wf,  const unsigned short* __restrict__ Wb,
    float* __restrict__ part)
{
    __shared__ unsigned short As[2][128 * 32];
    __shared__ unsigned short Bs[2][64 * 32];
    const int tid = threadIdx.x, wave = tid >> 6, lane = tid & 63;
    const int bm = blockIdx.x * 128;
    const int dir = blockIdx.y >> 2, sp = blockIdx.y & 3;
    const unsigned short* A = dir ? A_b : A_f;
    const unsigned short* W = dir ? Wb  : Wf;
    float* Cp = part + (size_t)blockIdx.y * MM * 64;
    const int kbeg = sp * 256, kend = kbeg + 256;

    const int strow = lane & 15;
    const int stkc  = lane >> 4;
    const int frow = lane & 15;
    const int fkc  = lane >> 4;

    floatx4 acc[2][4];
    #pragma unroll
    for (int i = 0; i < 2; ++i)
        #pragma unroll
        for (int j = 0; j < 4; ++j)
            acc[i][j] = (floatx4){0.f, 0.f, 0.f, 0.f};

    for (int k0 = kbeg; k0 < kend; k0 += 64) {
        __syncthreads();
        #pragma unroll
        for (int hh = 0; hh < 2; ++hh) {
            #pragma unroll
            for (int q = 0; q < 2; ++q) {
                int g = wave * 2 + q;
                GLOAD_LDS16(A + (size_t)(bm + g * 16 + strow) * DINNER + k0 + hh * 32 + stkc * 8,
                            As[hh] + g * 512);
            }
            GLOAD_LDS16(W + (size_t)(wave * 16 + strow) * DINNER + k0 + hh * 32 + stkc * 8,
                        Bs[hh] + wave * 512);
        }
        __syncthreads();

        #pragma unroll
        for (int hh = 0; hh < 2; ++hh) {
            bf16x8 af[2], bfr[4];
            #pragma unroll
            for (int i = 0; i < 2; ++i)
                af[i] = *(const bf16x8*)(As[hh] + (wave * 2 + i) * 512 + fkc * 128 + frow * 8);
            #pragma unroll
            for (int j = 0; j < 4; ++j)
                bfr[j] = *(const bf16x8*)(Bs[hh] + j * 512 + fkc * 128 + frow * 8);
            #pragma unroll
            for (int i = 0; i < 2; ++i)
                #pragma unroll
                for (int j = 0; j < 4; ++j)
                    acc[i][j] = __builtin_amdgcn_mfma_f32_16x16x32_bf16(
                        af[i], bfr[j], acc[i][j], 0, 0, 0);
        }
    }

    const int orow0 = bm + wave * 32 + (lane >> 4) * 4;
    #pragma unroll
    for (int j = 0; j < 4; ++j) {
        const int col = (lane & 15) + j * 16;
        #pragma unroll
        for (int i = 0; i < 2; ++i)
            #pragma unroll
            for (int r = 0; r < 4; ++r)
                Cp[(size_t)(orow0 + i * 16 + r) * 64 + col] = acc[i][j][r];
    }
}

// ---------------------------------------------------------------------------
// xproj reduce: cols 0..31 -> dbc[m][32] (dt rows); cols 32..63 -> bct[m][32].
// ---------------------------------------------------------------------------
__global__ __launch_bounds__(256) void xproj_reduce_kernel(
    const float* __restrict__ part,
    float* __restrict__ dbc_f, float* __restrict__ dbc_b,
    float* __restrict__ bct_f, float* __restrict__ bct_b)
{
    const int dir = blockIdx.y;
    const int i = (blockIdx.x * 256 + threadIdx.x) * 4;
    const float* p = part + (size_t)dir * 4 * (MM * 64);
    float4 a = *(const float4*)(p + i);
    #pragma unroll
    for (int s = 1; s < 4; ++s) {
        float4 t = *(const float4*)(p + (size_t)s * (MM * 64) + i);
        a.x += t.x; a.y += t.y; a.z += t.z; a.w += t.w;
    }
    const int m = i >> 6, c = i & 63;
    if (c < 32) {
        float* dbc = dir ? dbc_b : dbc_f;
        *(float4*)(dbc + (size_t)m * 32 + c) = a;
    } else {
        float* bct = dir ? bct_b : bct_f;
        *(float4*)(bct + (size_t)m * 32 + (c - 32)) = a;
    }
}

// ---------------------------------------------------------------------------
// Batched fp32 GEMM w/ softplus + row bias (dt-proj), bf16 output.
// ---------------------------------------------------------------------------
__global__ __launch_bounds__(256) void dtproj_batch_kernel(
    int M, int N, int K,
    const float* __restrict__ A0, const float* __restrict__ A1, int lda,
    const float* __restrict__ B0, const float* __restrict__ B1, int ldb,
    const float* __restrict__ bias0, const float* __restrict__ bias1,
    unsigned short* __restrict__ C0, unsigned short* __restrict__ C1, int ldc)
{
    __shared__ float As[16][64];
    __shared__ float Bs[16][64];
    const int z = blockIdx.z;
    const float* A = z ? A1 : A0;
    const float* B = z ? B1 : B0;
    const float* biasR = z ? bias1 : bias0;
    unsigned short* C = z ? C1 : C0;
    const int tid = threadIdx.x;
    const int tx = tid & 15, ty = tid >> 4;
    const int bm = blockIdx.y * 64, bn = blockIdx.x * 64;
    const int lm = tid & 63;
    const int lk = (tid >> 6) * 4;
    const float* Arow = A + (size_t)(bm + lm) * lda + lk;
    const float* Brow = B + (size_t)(bn + lm) * ldb + lk;
    float acc[4][4] = {};
    for (int k0 = 0; k0 < K; k0 += 16) {
        float4 av = *(const float4*)(Arow + k0);
        float4 bv = *(const float4*)(Brow + k0);
        __syncthreads();
        As[lk+0][lm] = av.x; As[lk+1][lm] = av.y; As[lk+2][lm] = av.z; As[lk+3][lm] = av.w;
        Bs[lk+0][lm] = bv.x; Bs[lk+1][lm] = bv.y; Bs[lk+2][lm] = bv.z; Bs[lk+3][lm] = bv.w;
        __syncthreads();
        #pragma unroll
        for (int k = 0; k < 16; ++k) {
            float4 a = *(const float4*)(&As[k][ty*4]);
            float4 b = *(const float4*)(&Bs[k][tx*4]);
            float ar[4] = {a.x,a.y,a.z,a.w};
            float br[4] = {b.x,b.y,b.z,b.w};
            #pragma unroll
            for (int i = 0; i < 4; ++i)
                #pragma unroll
                for (int j = 0; j < 4; ++j)
                    acc[i][j] = fmaf(ar[i], br[j], acc[i][j]);
        }
    }
    const int row0 = bm + ty*4, col0 = bn + tx*4;
    #pragma unroll
    for (int i = 0; i < 4; ++i) {
        float br = biasR[row0 + i];
        ushort4v o;
        #pragma unroll
        for (int j = 0; j < 4; ++j) {
            float t = acc[i][j] + br;
            o[j] = f2bf(fmaxf(t, 0.f) + log1pf(__expf(-fabsf(t))));
        }
        *(ushort4v*)(C + (size_t)(row0 + i) * ldc + col0) = o;
    }
}

// ---------------------------------------------------------------------------
// Segmented casts: 5 pre-GEMM arrays -> one contiguous bf16 block.
// ---------------------------------------------------------------------------
__global__ __launch_bounds__(256) void cast_pre_kernel(
    const float* __restrict__ x, const float* __restrict__ w0,
    const float* __restrict__ w1, const float* __restrict__ xp0,
    const float* __restrict__ xp1, unsigned short* __restrict__ dst)
{
    int i = (blockIdx.x * 256 + threadIdx.x) * 8;
    const float* src; int off;
    if      (i < 1048576) { src = x;   off = 0; }
    else if (i < 2097152) { src = w0;  off = 1048576; }
    else if (i < 3145728) { src = w1;  off = 2097152; }
    else if (i < 3211264) { src = xp0; off = 3145728; }
    else                  { src = xp1; off = 3211264; }
    float4 a = *(const float4*)(src + i - off);
    float4 b = *(const float4*)(src + i - off + 4);
    ushort8v o;
    o[0] = f2bf(a.x); o[1] = f2bf(a.y); o[2] = f2bf(a.z); o[3] = f2bf(a.w);
    o[4] = f2bf(b.x); o[5] = f2bf(b.y); o[6] = f2bf(b.z); o[7] = f2bf(b.w);
    *(ushort8v*)(dst + i) = o;
}

// Segments: outW_f(524288) outW_b(524288) W1(1048576) W2(1048576)
__global__ __launch_bounds__(256) void cast_post_kernel(
    const float* __restrict__ w0, const float* __restrict__ w1,
    const float* __restrict__ w2, const float* __restrict__ w3,
    unsigned short* __restrict__ dst)
{
    int i = (blockIdx.x * 256 + threadIdx.x) * 8;
    const float* src; int off;
    if      (i < 524288)  { src = w0; off = 0; }
    else if (i < 1048576) { src = w1; off = 524288; }
    else if (i < 2097152) { src = w2; off = 1048576; }
    else                  { src = w3; off = 2097152; }
    float4 a = *(const float4*)(src + i - off);
    float4 b = *(const float4*)(src + i - off + 4);
    ushort8v o;
    o[0] = f2bf(a.x); o[1] = f2bf(a.y); o[2] = f2bf(a.z); o[3] = f2bf(a.w);
    o[4] = f2bf(b.x); o[5] = f2bf(b.y); o[6] = f2bf(b.z); o[7] = f2bf(b.w);
    *(ushort8v*)(dst + i) = o;
}

// ---------------------------------------------------------------------------
// Fused depthwise conv + bias + silu + transpose (bf16 x input):
// writes xm[m][d] and xmT[d][m] (bf16). 32x32 tile, blockIdx.z = dir.
// ---------------------------------------------------------------------------
__global__ __launch_bounds__(256) void conv_silu_tr_kernel(
    const unsigned short* __restrict__ x_f, const unsigned short* __restrict__ x_b,
    const float* __restrict__ Wf,  const float* __restrict__ Wb,
    const float* __restrict__ cbf, const float* __restrict__ cbb,
    unsigned short* __restrict__ of,  unsigned short* __restrict__ ob,
    unsigned short* __restrict__ otf, unsigned short* __restrict__ otb)
{
    __shared__ unsigned short t[32][34];
    const int dir = blockIdx.z;
    const unsigned short* xo = dir ? x_b : x_f;
    const float* convW = dir ? Wb : Wf;
    const float* convb = dir ? cbb : cbf;
    unsigned short* xm  = dir ? ob : of;
    unsigned short* xmT = dir ? otb : otf;
    const int m0 = blockIdx.x * 32, d0 = blockIdx.y * 32;
    const int tx = threadIdx.x & 31, ty = threadIdx.x >> 5;
    const int d = d0 + tx;
    float4 wv = *(const float4*)(convW + d * 4);
    float w[4] = {wv.x, wv.y, wv.z, wv.w};
    const float cb = convb[d];
    #pragma unroll
    for (int rr = 0; rr < 32; rr += 8) {
        int m = m0 + ty + rr;
        int b = m >> 10, l = m & (SEQ - 1);
        float acc = cb;
        #pragma unroll
        for (int j = 0; j < 4; ++j) {
            int p = dir ? (l + 3 - j) : (l - 3 + j);
            if (p >= 0 && p < SEQ)
                acc = fmaf(bf2f(xo[(size_t)(b * SEQ + p) * DINNER + d]), w[j], acc);
        }
        float sig = 1.f / (1.f + __expf(-acc));
        unsigned short v = f2bf(acc * sig);
        xm[(size_t)m * DINNER + d] = v;
        t[ty + rr][tx] = v;
    }
    __syncthreads();
    #pragma unroll
    for (int rr = 0; rr < 32; rr += 8)
        xmT[(size_t)(d0 + ty + rr) * MM + m0 + tx] = t[tx][ty + rr];
}

// ---------------------------------------------------------------------------
// Scan pass 1: local scan from zero state, 4 states per thread.
// ---------------------------------------------------------------------------
template<int DIR>
__device__ __forceinline__ void pass1_body(
    const unsigned short* __restrict__ deltaT, const unsigned short* __restrict__ xmT,
    const float* __restrict__ bct, const float* __restrict__ Alog,
    const float* __restrict__ Dv,
    unsigned short* __restrict__ y0T, float* __restrict__ cumT,
    float* __restrict__ Pout, float* __restrict__ Hout)
{
    const int tid = threadIdx.x;
    const int sq = tid & 3;
    const int dloc = tid >> 2;
    const int d = blockIdx.x * 64 + dloc;
    const int b = blockIdx.y / NCHUNK;
    const int c = blockIdx.y % NCHUNK;

    float4 Av = *(const float4*)(Alog + d * DSTATE + sq * 4);
    const float A0 = -__expf(Av.x), A1 = -__expf(Av.y);
    const float A2 = -__expf(Av.z), A3 = -__expf(Av.w);
    const float Dp = Dv[d];
    const unsigned short* dRow = deltaT + (size_t)d * MM + b * SEQ;
    const unsigned short* xRow = xmT + (size_t)d * MM + b * SEQ;
    const float* bcRow = bct + (size_t)(b * SEQ) * 32 + sq * 4;
    unsigned short* yRow = y0T + (size_t)d * MM + b * SEQ;
    float* uRow = cumT + (size_t)d * MM + b * SEQ;

    float h0 = 0.f, h1 = 0.f, h2 = 0.f, h3 = 0.f, sdl = 0.f;
    const int segBase = DIR ? (SEQ - CHUNK - c * CHUNK) : (c * CHUNK);
    for (int ii = 0; ii < CHUNK; ii += 8) {
        const int off = DIR ? (segBase + (CHUNK - 8) - ii) : (segBase + ii);
        ushort8v dl8 = *(const ushort8v*)(dRow + off);
        ushort8v x8  = *(const ushort8v*)(xRow + off);
        float yv[8], cu[8];
        #pragma unroll
        for (int u = 0; u < 8; ++u) {
            const int t = DIR ? (7 - u) : u;
            float4 Bv = *(const float4*)(bcRow + (size_t)(off + t) * 32);
            float4 Cv = *(const float4*)(bcRow + (size_t)(off + t) * 32 + 16);
            float dlv = bf2f(dl8[t]);
            float xv  = bf2f(x8[t]);
            sdl += dlv;
            float dx = dlv * xv;
            h0 = fmaf(__expf(dlv * A0), h0, dx * Bv.x);
            h1 = fmaf(__expf(dlv * A1), h1, dx * Bv.y);
            h2 = fmaf(__expf(dlv * A2), h2, dx * Bv.z);
            h3 = fmaf(__expf(dlv * A3), h3, dx * Bv.w);
            float part = h0 * Cv.x + h1 * Cv.y + h2 * Cv.z + h3 * Cv.w;
            part = quadsum4(part);
            yv[t] = fmaf(xv, Dp, part);
            cu[t] = sdl;
        }
        if (sq == 0) {
            ushort8v y8;
            #pragma unroll
            for (int u = 0; u < 8; ++u) y8[u] = f2bf(yv[u]);
            *(ushort8v*)(yRow + off) = y8;
            *(float4*)(uRow + off)     = (float4){cu[0], cu[1], cu[2], cu[3]};
            *(float4*)(uRow + off + 4) = (float4){cu[4], cu[5], cu[6], cu[7]};
        }
    }
    const size_t g4 = ((size_t)(DIR * BATCH + b) * DINNER + d) * DSTATE + sq * 4;
    *(float4*)(Pout + (size_t)c * GTOT + g4) =
        (float4){__expf(sdl * A0), __expf(sdl * A1), __expf(sdl * A2), __expf(sdl * A3)};
    *(float4*)(Hout + (size_t)c * GTOT + g4) = (float4){h0, h1, h2, h3};
}

__global__ __launch_bounds__(256) void scan_pass1_kernel(
    const unsigned short* __restrict__ dT_f, const unsigned short* __restrict__ dT_b,
    const unsigned short* __restrict__ xT_f, const unsigned short* __restrict__ xT_b,
    const float* __restrict__ bct_f, const float* __restrict__ bct_b,
    const float* __restrict__ Alog_f, const float* __restrict__ Alog_b,
    const float* __restrict__ D_f, const float* __restrict__ D_b,
    unsigned short* __restrict__ y0T_f, unsigned short* __restrict__ y0T_b,
    float* __restrict__ cumT_f, float* __restrict__ cumT_b,
    float* __restrict__ Pout, float* __restrict__ Hout)
{
    if (blockIdx.z == 0)
        pass1_body<0>(dT_f, xT_f, bct_f, Alog_f, D_f, y0T_f, cumT_f, Pout, Hout);
    else
        pass1_body<1>(dT_b, xT_b, bct_b, Alog_b, D_b, y0T_b, cumT_b, Pout, Hout);
}

// ---------------------------------------------------------------------------
// Phase 2: sequential combine over chunks (preloaded P/H).
// ---------------------------------------------------------------------------
__global__ __launch_bounds__(256) void scan_carry_kernel(
    const float* __restrict__ P, const float* __restrict__ H,
    float* __restrict__ carry)
{
    const int g = blockIdx.x * 256 + threadIdx.x;
    float p[NCHUNK], hh[NCHUNK];
    #pragma unroll
    for (int c = 0; c < NCHUNK; ++c) {
        p[c]  = P[(size_t)c * GTOT + g];
        hh[c] = H[(size_t)c * GTOT + g];
    }
    float h = 0.f;
    #pragma unroll
    for (int c = 0; c < NCHUNK; ++c) {
        carry[(size_t)c * GTOT + g] = h;
        h = fmaf(p[c], h, hh[c]);
    }
}

// ---------------------------------------------------------------------------
// Correction pass: y = y0 + sum_s C*carry*exp(A*cumdl); *= silu(z) (bf16 z);
// transpose -> ybf[m][d]. blockIdx.z = dir.
// ---------------------------------------------------------------------------
__global__ __launch_bounds__(256) void scan_correct_kernel(
    const unsigned short* __restrict__ y0T_f, const unsigned short* __restrict__ y0T_b,
    const float* __restrict__ cumT_f, const float* __restrict__ cumT_b,
    const float* __restrict__ bct_f, const float* __restrict__ bct_b,
    const float* __restrict__ Alog_f, const float* __restrict__ Alog_b,
    const float* __restrict__ carry,
    const unsigned short* __restrict__ z_f, const unsigned short* __restrict__ z_b,
    unsigned short* __restrict__ ybf_f, unsigned short* __restrict__ ybf_b)
{
    __shared__ float Cs[16][33];
    __shared__ float Asm[32][16];
    __shared__ float Cy[32][16];
    __shared__ float t[32][33];

    const int dir = blockIdx.z;
    const unsigned short* y0T = dir ? y0T_b : y0T_f;
    const float* cumT = dir ? cumT_b : cumT_f;
    const float* bct  = dir ? bct_b  : bct_f;
    const float* Alog = dir ? Alog_b : Alog_f;
    const unsigned short* zon = dir ? z_b : z_f;
    unsigned short* ybf = dir ? ybf_b : ybf_f;

    const int m0 = blockIdx.x * 32, d0 = blockIdx.y * 32;
    const int b = m0 >> 10;
    const int l0 = m0 & (SEQ - 1);
    const int c = dir ? ((SEQ - 1 - l0) >> 6) : (l0 >> 6);

    for (int idx = threadIdx.x; idx < 512; idx += 256) {
        int s1 = idx & 15, ml = idx >> 4;
        Cs[s1][ml] = bct[(size_t)(m0 + ml) * 32 + 16 + s1];
        int dl2 = idx >> 4, s2 = idx & 15;
        Asm[dl2][s2] = -__expf(Alog[(d0 + dl2) * DSTATE + s2]);
        Cy[dl2][s2] = carry[(size_t)c * GTOT
            + ((size_t)(dir * BATCH + b) * DINNER + d0 + dl2) * DSTATE + s2];
    }
    __syncthreads();

    const int tx = threadIdx.x & 31, ty = threadIdx.x >> 5;
    #pragma unroll
    for (int rr = 0; rr < 32; rr += 8) {
        const int dloc = ty + rr;
        const size_t base = (size_t)(d0 + dloc) * MM + m0 + tx;
        float u  = cumT[base];
        float y0 = bf2f(y0T[base]);
        float corr = 0.f;
        #pragma unroll
        for (int s = 0; s < DSTATE; ++s)
            corr = fmaf(Cs[s][tx] * Cy[dloc][s], __expf(Asm[dloc][s] * u), corr);
        t[dloc][tx] = y0 + corr;
    }
    __syncthreads();
    #pragma unroll
    for (int rr = 0; rr < 32; rr += 8) {
        int m = m0 + ty + rr, d = d0 + tx;
        float z = bf2f(zon[(size_t)m * DINNER + d]);
        float sig = 1.f / (1.f + __expf(-z));
        ybf[(size_t)m * DINNER + d] = f2bf(t[tx][ty + rr] * (z * sig));
    }
}

// ---------------------------------------------------------------------------
// FF1 split-K2 reduce + bias + relu -> bf16 h.
// ---------------------------------------------------------------------------
__global__ __launch_bounds__(256) void reduce_ff1_kernel(
    const float* __restrict__ part, const float* __restrict__ bias,
    unsigned short* __restrict__ outh)
{
    const int i = (blockIdx.x * 256 + threadIdx.x) * 4;
    float4 a = *(const float4*)(part + i);
    float4 b = *(const float4*)(part + (size_t)MM * DFF + i);
    const int c = i & (DFF - 1);
    ushort4v o;
    o[0] = f2bf(fmaxf(a.x + b.x + bias[c],     0.f));
    o[1] = f2bf(fmaxf(a.y + b.y + bias[c + 1], 0.f));
    o[2] = f2bf(fmaxf(a.z + b.z + bias[c + 2], 0.f));
    o[3] = f2bf(fmaxf(a.w + b.w + bias[c + 3], 0.f));
    *(ushort4v*)(outh + i) = o;
}

// ---------------------------------------------------------------------------
// Fused out-proj split-K reduce (4 per dir) + dual LN -> bf16.
// part = [8][MM*DMODEL]: dir0 slices 0..3, dir1 slices 4..7.
// ---------------------------------------------------------------------------
__global__ __launch_bounds__(256) void ln_combine_fused_kernel(
    const float* __restrict__ xf, const float* __restrict__ part,
    const float* __restrict__ g1, const float* __restrict__ b1,
    const float* __restrict__ g2, const float* __restrict__ b2,
    unsigned short* __restrict__ out)
{
    const int m = blockIdx.x;
    const int tid = threadIdx.x;
    const size_t stride = (size_t)MM * DMODEL;
    const float* xr = xf + (size_t)m * DMODEL;
    const float* p = part + (size_t)m * DMODEL;
    float v1a = xr[tid], v1b = xr[tid + 256];
    float v2a = xr[tid], v2b = xr[tid + 256];
    #pragma unroll
    for (int k = 0; k < 4; ++k) {
        v1a += p[k * stride + tid];       v1b += p[k * stride + tid + 256];
        v2a += p[(4 + k) * stride + tid]; v2b += p[(4 + k) * stride + tid + 256];
    }
    float s1 = v1a + v1b, q1 = v1a*v1a + v1b*v1b;
    float s2 = v2a + v2b, q2 = v2a*v2a + v2b*v2b;
    #pragma unroll
    for (int off = 32; off; off >>= 1) {
        s1 += __shfl_xor(s1, off); q1 += __shfl_xor(q1, off);
        s2 += __shfl_xor(s2, off); q2 += __shfl_xor(q2, off);
    }
    __shared__ float sm[4][4];
    const int w = tid >> 6;
    if ((tid & 63) == 0) { sm[w][0] = s1; sm[w][1] = q1; sm[w][2] = s2; sm[w][3] = q2; }
    __syncthreads();
    s1 = sm[0][0] + sm[1][0] + sm[2][0] + sm[3][0];
    q1 = sm[0][1] + sm[1][1] + sm[2][1] + sm[3][1];
    s2 = sm[0][2] + sm[1][2] + sm[2][2] + sm[3][2];
    q2 = sm[0][3] + sm[1][3] + sm[2][3] + sm[3][3];
    const float inv = 1.f / DMODEL;
    float mu1 = s1 * inv, mu2 = s2 * inv;
    float rs1 = rsqrtf(q1 * inv - mu1 * mu1 + 1e-5f);
    float rs2 = rsqrtf(q2 * inv - mu2 * mu2 + 1e-5f);
    unsigned short* orow = out + (size_t)m * DMODEL;
    orow[tid]       = f2bf((v1a - mu1) * rs1 * g1[tid]       + b1[tid]
                         + (v2a - mu2) * rs2 * g2[tid]       + b2[tid]);
    orow[tid + 256] = f2bf((v1b - mu1) * rs1 * g1[tid + 256] + b1[tid + 256]
                         + (v2b - mu2) * rs2 * g2[tid + 256] + b2[tid + 256]);
}

// ---------------------------------------------------------------------------
// Fused FF2 split-K8 reduce + bias + LN(2*ff).
// ---------------------------------------------------------------------------
__global__ __launch_bounds__(256) void ln_final_fused_kernel(
    const float* __restrict__ part, const float* __restrict__ bias,
    const float* __restrict__ g, const float* __restrict__ b,
    float* __restrict__ out)
{
    const int m = blockIdx.x;
    const int tid = threadIdx.x;
    const size_t stride = (size_t)MM * DMODEL;
    const float* p = part + (size_t)m * DMODEL;
    float fa = bias[tid], fb = bias[tid + 256];
    #pragma unroll
    for (int k = 0; k < 8; ++k) {
        fa += p[k * stride + tid];
        fb += p[k * stride + tid + 256];
    }
    float va = 2.f * fa, vb = 2.f * fb;
    float s = va + vb, q = va*va + vb*vb;
    #pragma unroll
    for (int off = 32; off; off >>= 1) {
        s += __shfl_xor(s, off); q += __shfl_xor(q, off);
    }
    __shared__ float sm[4][2];
    const int w = tid >> 6;
    if ((tid & 63) == 0) { sm[w][0] = s; sm[w][1] = q; }
    __syncthreads();
    s = sm[0][0] + sm[1][0] + sm[2][0] + sm[3][0];
    q = sm[0][1] + sm[1][1] + sm[2][1] + sm[3][1];
    const float inv = 1.f / DMODEL;
    float mu = s * inv;
    float rs = rsqrtf(q * inv - mu * mu + 1e-5f);
    float* orow = out + (size_t)m * DMODEL;
    orow[tid]       = (va - mu) * rs * g[tid]       + b[tid];
    orow[tid + 256] = (vb - mu) * rs * g[tid + 256] + b[tid + 256];
}

// ---------------------------------------------------------------------------
extern "C" void kernel_launch(void* const* d_in, const int* in_sizes, int n_in,
                              void* d_out, int out_size, void* d_ws, size_t ws_size,
                              hipStream_t stream)
{
    const float* x         = (const float*)d_in[0];
    const float* fm_in_W   = (const float*)d_in[1];
    const float* fm_conv_W = (const float*)d_in[2];
    const float* fm_conv_b = (const float*)d_in[3];
    const float* fm_xproj_W= (const float*)d_in[4];
    const float* fm_dt_W   = (const float*)d_in[5];
    const float* fm_dt_b   = (const float*)d_in[6];
    const float* fm_A_log  = (const float*)d_in[7];
    const float* fm_D      = (const float*)d_in[8];
    const float* fm_out_W  = (const float*)d_in[9];
    const float* bm_in_W   = (const float*)d_in[10];
    const float* bm_conv_W = (const float*)d_in[11];
    const float* bm_conv_b = (const float*)d_in[12];
    const float* bm_xproj_W= (const float*)d_in[13];
    const float* bm_dt_W   = (const float*)d_in[14];
    const float* bm_dt_b   = (const float*)d_in[15];
    const float* bm_A_log  = (const float*)d_in[16];
    const float* bm_D      = (const float*)d_in[17];
    const float* bm_out_W  = (const float*)d_in[18];
    const float* ln1_g     = (const float*)d_in[19];
    const float* ln1_b     = (const float*)d_in[20];
    const float* ln2_g     = (const float*)d_in[21];
    const float* ln2_b     = (const float*)d_in[22];
    const float* ln3_g     = (const float*)d_in[23];
    const float* ln3_b     = (const float*)d_in[24];
    const float* ff_W1     = (const float*)d_in[25];
    const float* ff_b1     = (const float*)d_in[26];
    const float* ff_W2     = (const float*)d_in[27];
    const float* ff_b2     = (const float*)d_in[28];
    float* out = (float*)d_out;

    // ---- Workspace layout (floats; ~96 MB) ----
    float* ws = (float*)d_ws;
    size_t o = 0;
    unsigned short* xbf_f = (unsigned short*)(ws + o); o += (size_t)MM * DINNER / 2;  // bf16 x-half
    unsigned short* xbf_b = (unsigned short*)(ws + o); o += (size_t)MM * DINNER / 2;
    unsigned short* zbf_f = (unsigned short*)(ws + o); o += (size_t)MM * DINNER / 2;  // bf16 z-half
    unsigned short* zbf_b = (unsigned short*)(ws + o); o += (size_t)MM * DINNER / 2;
    unsigned short* xm_bf_f = (unsigned short*)(ws + o); o += (size_t)MM * DINNER / 2;
    unsigned short* xm_bf_b = (unsigned short*)(ws + o); o += (size_t)MM * DINNER / 2;
    unsigned short* xmT_f   = (unsigned short*)(ws + o); o += (size_t)MM * DINNER / 2;
    unsigned short* xmT_b   = (unsigned short*)(ws + o); o += (size_t)MM * DINNER / 2;
    unsigned short* deltaT_f= (unsigned short*)(ws + o); o += (size_t)MM * DINNER / 2;
    unsigned short* deltaT_b= (unsigned short*)(ws + o); o += (size_t)MM * DINNER / 2;
    float* dbc_f    = ws + o; o += (size_t)MM * 32;
    float* dbc_b    = ws + o; o += (size_t)MM * 32;
    float* bct_f    = ws + o; o += (size_t)MM * 32;
    float* bct_b    = ws + o; o += (size_t)MM * 32;
    unsigned short* y0T_f = (unsigned short*)(ws + o); o += (size_t)MM * DINNER / 2;
    unsigned short* y0T_b = (unsigned short*)(ws + o); o += (size_t)MM * DINNER / 2;
    float* scanP    = ws + o; o += (size_t)NCHUNK * (GTOT / 16) * 16;  // 1,048,576
    float* scanH    = ws + o; o += (size_t)NCHUNK * (GTOT / 16) * 16;
    float* scanCy   = ws + o; o += (size_t)NCHUNK * (GTOT / 16) * 16;
    float* gpart    = ws + o; o += (size_t)8 * MM * DMODEL;            // 8,388,608

    // ---- Overlays (sequenced reuse) ----
    // gpart timeline: xproj partials (1.05M) -> cumT (4.19M, written by pass1)
    //   -> out-proj partials (8.39M) -> FF1 partials (8.39M) -> FF2 partials.
    float* cumT_f = gpart;
    float* cumT_b = gpart + (size_t)MM * DINNER;
    unsigned short* xin_bf     = (unsigned short*)scanP;   // dead until pass1
    unsigned short* fm_inW_bf  = xin_bf + 1048576;
    unsigned short* bm_inW_bf  = fm_inW_bf + 1048576;
    unsigned short* fm_xpW_bf  = bm_inW_bf + 1048576;
    unsigned short* bm_xpW_bf  = fm_xpW_bf + 65536;
    unsigned short* ybf_f = (unsigned short*)scanP;        // P/H dead after carry
    unsigned short* ybf_b = (unsigned short*)scanH;
    unsigned short* fm_outW_bf = (unsigned short*)zbf_f;   // z dead after correct
    unsigned short* bm_outW_bf = fm_outW_bf + 524288;      // spans zbf_f..zbf_b (2.1M fl)
    unsigned short* W1_bf      = bm_outW_bf + 524288;
    unsigned short* W2_bf      = W1_bf + 1048576;
    unsigned short* outsum_bf  = (unsigned short*)xbf_f;   // x-half dead after conv
    unsigned short* h_bf = (unsigned short*)deltaT_f;      // deltaT dead after pass1

    // ---- 0. pre-GEMM casts ----
    cast_pre_kernel<<<3276800 / 2048, 256, 0, stream>>>(
        x, fm_in_W, bm_in_W, fm_xproj_W, bm_xproj_W, xin_bf);

    // ---- 1. in-proj GEMMs, bf16 split x/z outputs, both dirs (512 blocks) ----
    gemm_inproj_kernel<<<dim3(2048/128, MM/128, 2), 256, 0, stream>>>(
        xin_bf, fm_inW_bf, bm_inW_bf, xbf_f, zbf_f, xbf_b, zbf_b);

    // ---- 2. fused conv + silu + transpose -> xm[m][d], xmT[d][m] ----
    conv_silu_tr_kernel<<<dim3(MM/32, DINNER/32, 2), 256, 0, stream>>>(
        xbf_f, xbf_b, fm_conv_W, bm_conv_W, fm_conv_b, bm_conv_b,
        xm_bf_f, xm_bf_b, xmT_f, xmT_b);

    // ---- 3. x-proj: split-K x4, both dirs + reduce -> dbc[m][32], bct[m][32] ----
    xproj_splitk_kernel<<<dim3(MM/128, 8), 256, 0, stream>>>(
        xm_bf_f, xm_bf_b, fm_xpW_bf, bm_xpW_bf, gpart);
    xproj_reduce_kernel<<<dim3((MM*64)/1024, 2), 256, 0, stream>>>(
        gpart, dbc_f, dbc_b, bct_f, bct_b);

    // ---- 4. dt-proj, both dirs -> deltaT bf16 [d][m], softplus ----
    dtproj_batch_kernel<<<dim3(MM/64, DINNER/64, 2), 256, 0, stream>>>(
        DINNER, MM, DTRANK, fm_dt_W, bm_dt_W, DTRANK, dbc_f, dbc_b, 32,
        fm_dt_b, bm_dt_b, deltaT_f, deltaT_b, MM);

    // ---- 5. scan: pass1 (4 states/thread) + carry + parallel correction ----
    scan_pass1_kernel<<<dim3(DINNER/64, BATCH*NCHUNK, 2), 256, 0, stream>>>(
        deltaT_f, deltaT_b, xmT_f, xmT_b, bct_f, bct_b,
        fm_A_log, bm_A_log, fm_D, bm_D,
        y0T_f, y0T_b, cumT_f, cumT_b, scanP, scanH);
    scan_carry_kernel<<<GTOT/256, 256, 0, stream>>>(scanP, scanH, scanCy);
    scan_correct_kernel<<<dim3(MM/32, DINNER/32, 2), 256, 0, stream>>>(
        y0T_f, y0T_b, cumT_f, cumT_b, bct_f, bct_b, fm_A_log, bm_A_log,
        scanCy, zbf_f, zbf_b, ybf_f, ybf_b);

    // ---- 6. post weight casts (z region dead) ----
    cast_post_kernel<<<3145728 / 2048, 256, 0, stream>>>(
        fm_out_W, bm_out_W, ff_W1, ff_W2, fm_outW_bf);

    // ---- 7. out-proj: dirs x splitK4 (512 blocks) -> gpart ----
    gemm_mfma_splitk<4><<<dim3(DMODEL/128, MM/128, 8), 256, 0, stream>>>(
        MM, DMODEL, DINNER, ybf_f, ybf_b, DINNER, fm_outW_bf, bm_outW_bf, DINNER,
        gpart, DMODEL);

    // ---- 8. fused reduce (4/dir) + dual LN -> bf16 outsum ----
    ln_combine_fused_kernel<<<MM, 256, 0, stream>>>(
        x, gpart, ln1_g, ln1_b, ln2_g, ln2_b, outsum_bf);

    // ---- 9. FF1: splitK2 (512 blocks) -> gpart; reduce+bias+relu -> h_bf ----
    gemm_mfma_splitk<2><<<dim3(DFF/128, MM/128, 2), 256, 0, stream>>>(
        MM, DFF, DMODEL, outsum_bf, outsum_bf, DMODEL, W1_bf, W1_bf, DMODEL,
        gpart, DFF);
    reduce_ff1_kernel<<<(MM*DFF)/1024, 256, 0, stream>>>(gpart, ff_b1, h_bf);

    // ---- 10. FF2: splitK8 (512 blocks) -> gpart ----
    gemm_mfma_splitk<8><<<dim3(DMODEL/128, MM/128, 8), 256, 0, stream>>>(
        MM, DMODEL, DFF, h_bf, h_bf, DFF, W2_bf, W2_bf, DFF, gpart, DMODEL);

    // ---- 11. fused reduce (8) + bias + final LN(2*ff) ----
    ln_final_fused_kernel<<<MM, 256, 0, stream>>>(
        gpart, ff_b2, ln3_g, ln3_b, out);
}

// Round 13
// 301.719 us; speedup vs baseline: 1.0213x; 1.0213x over previous
//
#include <hip/hip_runtime.h>
#include <hip/hip_bf16.h>
#include <math.h>

// Problem constants
#define MM 2048        // B*W flattened rows
#define BATCH 2
#define SEQ 1024
#define DMODEL 512
#define DINNER 1024
#define DSTATE 16
#define DTRANK 32
#define DFF 2048

// Chunked-scan constants
#define NCHUNK 16
#define CHUNK 64
#define GTOT 65536          // 2 dirs * BATCH * DINNER * DSTATE

typedef short bf16x8 __attribute__((ext_vector_type(8)));
typedef float floatx4 __attribute__((ext_vector_type(4)));
typedef unsigned short ushort8v __attribute__((ext_vector_type(8)));
typedef unsigned short ushort4v __attribute__((ext_vector_type(4)));

__device__ __forceinline__ unsigned short f2bf(float f) {
    union { float f; unsigned u; } v; v.f = f;
    unsigned r = v.u + 0x7FFF + ((v.u >> 16) & 1);
    return (unsigned short)(r >> 16);
}
__device__ __forceinline__ float bf2f(unsigned short u) {
    union { unsigned u; float f; } v; v.u = ((unsigned)u) << 16; return v.f;
}

// Sum across each 4-lane quad via DPP quad_perm adds (VALU-only).
__device__ __forceinline__ float quadsum4(float x) {
    union { float f; int i; } a, b;
    a.f = x;
    b.i = __builtin_amdgcn_update_dpp(0, a.i, 0xB1, 0xF, 0xF, false); a.f += b.f; // [1,0,3,2]
    b.i = __builtin_amdgcn_update_dpp(0, a.i, 0x4E, 0xF, 0xF, false); a.f += b.f; // [2,3,0,1]
    return a.f;
}

#define GLOAD_LDS16(gp, lp) __builtin_amdgcn_global_load_lds( \
    (const __attribute__((address_space(1))) unsigned int*)(gp), \
    (__attribute__((address_space(3))) unsigned int*)(lp), 16, 0, 0)

// NOTES (measured on this problem):
// - Single-buffered barrier-stage-barrier K-loops ONLY: LDS double-buffering
//   races (round-9 post-timing divergence; waitcnt tied to aliasing ds_reads).
// - BK=64 (two halves staged before one barrier) is safe and neutral-to-
//   slightly-positive vs BK=32 (round 11).
// - Split-K beyond ~1 block/CU REGRESSES: fp32 partial traffic scales with
//   NSPLIT and cancels the occupancy gain (round 12). Optimum here:
//   out-proj splitK2/dir, FF2 splitK4, FF1 direct.

// ---------------------------------------------------------------------------
// Batched direct bf16 MFMA GEMM: C[z][M,N] = epi(A[z] @ B[z]^T + bias)
// 128x128 tile, BK=64. Conflict-free LDS. K % 64 == 0.
// ---------------------------------------------------------------------------
template<int EPI, int OUTBF16>
__global__ __launch_bounds__(256) void gemm_mfma_batch(
    int M, int N, int K,
    const unsigned short* __restrict__ A0, const unsigned short* __restrict__ A1, int lda,
    const unsigned short* __restrict__ B0, const unsigned short* __restrict__ B1, int ldb,
    const float* __restrict__ bias,
    void* __restrict__ C0, void* __restrict__ C1, int ldc)
{
    __shared__ unsigned short As[2][128 * 32];
    __shared__ unsigned short Bs[2][128 * 32];
    const int z = blockIdx.z;
    const unsigned short* A = z ? A1 : A0;
    const unsigned short* B = z ? B1 : B0;
    void* Cout = z ? C1 : C0;
    const int tid  = threadIdx.x;
    const int wave = tid >> 6;
    const int lane = tid & 63;
    const int bm = blockIdx.y * 128;
    const int bn = blockIdx.x * 128;

    const int strow = lane & 15;
    const int stkc  = lane >> 4;
    const int wr = wave >> 1, wc = wave & 1;
    const int frow = lane & 15;
    const int fkc  = lane >> 4;

    floatx4 acc[4][4];
    #pragma unroll
    for (int i = 0; i < 4; ++i)
        #pragma unroll
        for (int j = 0; j < 4; ++j)
            acc[i][j] = (floatx4){0.f, 0.f, 0.f, 0.f};

    for (int k0 = 0; k0 < K; k0 += 64) {
        __syncthreads();
        #pragma unroll
        for (int hh = 0; hh < 2; ++hh) {
            #pragma unroll
            for (int q = 0; q < 2; ++q) {
                int g = wave * 2 + q;
                GLOAD_LDS16(A + (size_t)(bm + g * 16 + strow) * lda + k0 + hh * 32 + stkc * 8,
                            As[hh] + g * 512);
            }
            #pragma unroll
            for (int q = 0; q < 2; ++q) {
                int g = wave * 2 + q;
                GLOAD_LDS16(B + (size_t)(bn + g * 16 + strow) * ldb + k0 + hh * 32 + stkc * 8,
                            Bs[hh] + g * 512);
            }
        }
        __syncthreads();

        #pragma unroll
        for (int hh = 0; hh < 2; ++hh) {
            bf16x8 af[4], bfr[4];
            #pragma unroll
            for (int i = 0; i < 4; ++i)
                af[i] = *(const bf16x8*)(As[hh] + (wr * 4 + i) * 512 + fkc * 128 + frow * 8);
            #pragma unroll
            for (int j = 0; j < 4; ++j)
                bfr[j] = *(const bf16x8*)(Bs[hh] + (wc * 4 + j) * 512 + fkc * 128 + frow * 8);
            #pragma unroll
            for (int i = 0; i < 4; ++i)
                #pragma unroll
                for (int j = 0; j < 4; ++j)
                    acc[i][j] = __builtin_amdgcn_mfma_f32_16x16x32_bf16(
                        af[i], bfr[j], acc[i][j], 0, 0, 0);
        }
    }

    const int orow0 = bm + wr * 64 + (lane >> 4) * 4;
    const int ocol0 = bn + wc * 64 + (lane & 15);
    #pragma unroll
    for (int j = 0; j < 4; ++j) {
        const int col = ocol0 + j * 16;
        const float bv = bias ? bias[col] : 0.f;
        #pragma unroll
        for (int i = 0; i < 4; ++i) {
            #pragma unroll
            for (int r = 0; r < 4; ++r) {
                int row = orow0 + i * 16 + r;
                float t = acc[i][j][r] + bv;
                if (EPI == 1) t = fmaxf(t, 0.f);
                if (OUTBF16)
                    ((unsigned short*)Cout)[(size_t)row * ldc + col] = f2bf(t);
                else
                    ((float*)Cout)[(size_t)row * ldc + col] = t;
            }
        }
    }
}

// ---------------------------------------------------------------------------
// In-proj GEMM (BK=64): writes bf16 x-half / z-half buffers (each [M][1024]).
// A shared across dirs; blockIdx.z = dir. M=MM, N=2048, K=512.
// ---------------------------------------------------------------------------
__global__ __launch_bounds__(256) void gemm_inproj_kernel(
    const unsigned short* __restrict__ A,
    const unsigned short* __restrict__ B0, const unsigned short* __restrict__ B1,
    unsigned short* __restrict__ Cx0, unsigned short* __restrict__ Cz0,
    unsigned short* __restrict__ Cx1, unsigned short* __restrict__ Cz1)
{
    __shared__ unsigned short As[2][128 * 32];
    __shared__ unsigned short Bs[2][128 * 32];
    const int z = blockIdx.z;
    const unsigned short* B = z ? B1 : B0;
    const int tid  = threadIdx.x;
    const int wave = tid >> 6;
    const int lane = tid & 63;
    const int bm = blockIdx.y * 128;
    const int bn = blockIdx.x * 128;

    const int strow = lane & 15;
    const int stkc  = lane >> 4;
    const int wr = wave >> 1, wc = wave & 1;
    const int frow = lane & 15;
    const int fkc  = lane >> 4;

    floatx4 acc[4][4];
    #pragma unroll
    for (int i = 0; i < 4; ++i)
        #pragma unroll
        for (int j = 0; j < 4; ++j)
            acc[i][j] = (floatx4){0.f, 0.f, 0.f, 0.f};

    for (int k0 = 0; k0 < DMODEL; k0 += 64) {
        __syncthreads();
        #pragma unroll
        for (int hh = 0; hh < 2; ++hh) {
            #pragma unroll
            for (int q = 0; q < 2; ++q) {
                int g = wave * 2 + q;
                GLOAD_LDS16(A + (size_t)(bm + g * 16 + strow) * DMODEL + k0 + hh * 32 + stkc * 8,
                            As[hh] + g * 512);
            }
            #pragma unroll
            for (int q = 0; q < 2; ++q) {
                int g = wave * 2 + q;
                GLOAD_LDS16(B + (size_t)(bn + g * 16 + strow) * DMODEL + k0 + hh * 32 + stkc * 8,
                            Bs[hh] + g * 512);
            }
        }
        __syncthreads();

        #pragma unroll
        for (int hh = 0; hh < 2; ++hh) {
            bf16x8 af[4], bfr[4];
            #pragma unroll
            for (int i = 0; i < 4; ++i)
                af[i] = *(const bf16x8*)(As[hh] + (wr * 4 + i) * 512 + fkc * 128 + frow * 8);
            #pragma unroll
            for (int j = 0; j < 4; ++j)
                bfr[j] = *(const bf16x8*)(Bs[hh] + (wc * 4 + j) * 512 + fkc * 128 + frow * 8);
            #pragma unroll
            for (int i = 0; i < 4; ++i)
                #pragma unroll
                for (int j = 0; j < 4; ++j)
                    acc[i][j] = __builtin_amdgcn_mfma_f32_16x16x32_bf16(
                        af[i], bfr[j], acc[i][j], 0, 0, 0);
        }
    }

    const int zh = bn >= DINNER;
    unsigned short* C = z ? (zh ? Cz1 : Cx1) : (zh ? Cz0 : Cx0);
    const int cb = zh ? DINNER : 0;
    const int orow0 = bm + wr * 64 + (lane >> 4) * 4;
    const int ocol0 = bn + wc * 64 + (lane & 15) - cb;
    #pragma unroll
    for (int j = 0; j < 4; ++j) {
        const int col = ocol0 + j * 16;
        #pragma unroll
        for (int i = 0; i < 4; ++i)
            #pragma unroll
            for (int r = 0; r < 4; ++r)
                C[(size_t)(orow0 + i * 16 + r) * DINNER + col] = f2bf(acc[i][j][r]);
    }
}

// ---------------------------------------------------------------------------
// Split-K batched MFMA GEMM (BK=64) -> fp32 partials part[z][M*ldc].
// z = dir*NSPLIT + sp. (K/NSPLIT) % 64 == 0.
// ---------------------------------------------------------------------------
template<int NSPLIT>
__global__ __launch_bounds__(256) void gemm_mfma_splitk(
    int M, int N, int K,
    const unsigned short* __restrict__ A0, const unsigned short* __restrict__ A1, int lda,
    const unsigned short* __restrict__ B0, const unsigned short* __restrict__ B1, int ldb,
    float* __restrict__ part, int ldc)
{
    __shared__ unsigned short As[2][128 * 32];
    __shared__ unsigned short Bs[2][128 * 32];
    const int z = blockIdx.z;
    const int dir = z / NSPLIT, sp = z % NSPLIT;
    const unsigned short* A = dir ? A1 : A0;
    const unsigned short* B = dir ? B1 : B0;
    float* Cp = part + (size_t)z * M * ldc;
    const int kbeg = sp * (K / NSPLIT);
    const int kend = kbeg + (K / NSPLIT);
    const int tid  = threadIdx.x;
    const int wave = tid >> 6;
    const int lane = tid & 63;
    const int bm = blockIdx.y * 128;
    const int bn = blockIdx.x * 128;

    const int strow = lane & 15;
    const int stkc  = lane >> 4;
    const int wr = wave >> 1, wc = wave & 1;
    const int frow = lane & 15;
    const int fkc  = lane >> 4;

    floatx4 acc[4][4];
    #pragma unroll
    for (int i = 0; i < 4; ++i)
        #pragma unroll
        for (int j = 0; j < 4; ++j)
            acc[i][j] = (floatx4){0.f, 0.f, 0.f, 0.f};

    for (int k0 = kbeg; k0 < kend; k0 += 64) {
        __syncthreads();
        #pragma unroll
        for (int hh = 0; hh < 2; ++hh) {
            #pragma unroll
            for (int q = 0; q < 2; ++q) {
                int g = wave * 2 + q;
                GLOAD_LDS16(A + (size_t)(bm + g * 16 + strow) * lda + k0 + hh * 32 + stkc * 8,
                            As[hh] + g * 512);
            }
            #pragma unroll
            for (int q = 0; q < 2; ++q) {
                int g = wave * 2 + q;
                GLOAD_LDS16(B + (size_t)(bn + g * 16 + strow) * ldb + k0 + hh * 32 + stkc * 8,
                            Bs[hh] + g * 512);
            }
        }
        __syncthreads();

        #pragma unroll
        for (int hh = 0; hh < 2; ++hh) {
            bf16x8 af[4], bfr[4];
            #pragma unroll
            for (int i = 0; i < 4; ++i)
                af[i] = *(const bf16x8*)(As[hh] + (wr * 4 + i) * 512 + fkc * 128 + frow * 8);
            #pragma unroll
            for (int j = 0; j < 4; ++j)
                bfr[j] = *(const bf16x8*)(Bs[hh] + (wc * 4 + j) * 512 + fkc * 128 + frow * 8);
            #pragma unroll
            for (int i = 0; i < 4; ++i)
                #pragma unroll
                for (int j = 0; j < 4; ++j)
                    acc[i][j] = __builtin_amdgcn_mfma_f32_16x16x32_bf16(
                        af[i], bfr[j], acc[i][j], 0, 0, 0);
        }
    }

    const int orow0 = bm + wr * 64 + (lane >> 4) * 4;
    const int ocol0 = bn + wc * 64 + (lane & 15);
    #pragma unroll
    for (int j = 0; j < 4; ++j) {
        const int col = ocol0 + j * 16;
        #pragma unroll
        for (int i = 0; i < 4; ++i)
            #pragma unroll
            for (int r = 0; r < 4; ++r)
                Cp[(size_t)(orow0 + i * 16 + r) * ldc + col] = acc[i][j][r];
    }
}

// ---------------------------------------------------------------------------
// xproj split-K MFMA (BK=64): tile 128(m) x 64(n), K slice 256.
// blockIdx.y = dir*4 + sp.
// ---------------------------------------------------------------------------
__global__ __launch_bounds__(256) void xproj_splitk_kernel(
    const unsigned short* __restrict__ A_f, const unsigned short* __restrict__ A_b,
    const unsigned short* __restrict__ Wf,  const unsigned short* __restrict__ Wb,
    float* __restrict__ part)
{
    __shared__ unsigned short As[2][128 * 32];
    __shared__ unsigned short Bs[2][64 * 32];
    const int tid = threadIdx.x, wave = tid >> 6, lane = tid & 63;
    const int bm = blockIdx.x * 128;
    const int dir = blockIdx.y >> 2, sp = blockIdx.y & 3;
    const unsigned short* A = dir ? A_b : A_f;
    const unsigned short* W = dir ? Wb  : Wf;
    float* Cp = part + (size_t)blockIdx.y * MM * 64;
    const int kbeg = sp * 256, kend = kbeg + 256;

    const int strow = lane & 15;
    const int stkc  = lane >> 4;
    const int frow = lane & 15;
    const int fkc  = lane >> 4;

    floatx4 acc[2][4];
    #pragma unroll
    for (int i = 0; i < 2; ++i)
        #pragma unroll
        for (int j = 0; j < 4; ++j)
            acc[i][j] = (floatx4){0.f, 0.f, 0.f, 0.f};

    for (int k0 = kbeg; k0 < kend; k0 += 64) {
        __syncthreads();
        #pragma unroll
        for (int hh = 0; hh < 2; ++hh) {
            #pragma unroll
            for (int q = 0; q < 2; ++q) {
                int g = wave * 2 + q;
                GLOAD_LDS16(A + (size_t)(bm + g * 16 + strow) * DINNER + k0 + hh * 32 + stkc * 8,
                            As[hh] + g * 512);
            }
            GLOAD_LDS16(W + (size_t)(wave * 16 + strow) * DINNER + k0 + hh * 32 + stkc * 8,
                        Bs[hh] + wave * 512);
        }
        __syncthreads();

        #pragma unroll
        for (int hh = 0; hh < 2; ++hh) {
            bf16x8 af[2], bfr[4];
            #pragma unroll
            for (int i = 0; i < 2; ++i)
                af[i] = *(const bf16x8*)(As[hh] + (wave * 2 + i) * 512 + fkc * 128 + frow * 8);
            #pragma unroll
            for (int j = 0; j < 4; ++j)
                bfr[j] = *(const bf16x8*)(Bs[hh] + j * 512 + fkc * 128 + frow * 8);
            #pragma unroll
            for (int i = 0; i < 2; ++i)
                #pragma unroll
                for (int j = 0; j < 4; ++j)
                    acc[i][j] = __builtin_amdgcn_mfma_f32_16x16x32_bf16(
                        af[i], bfr[j], acc[i][j], 0, 0, 0);
        }
    }

    const int orow0 = bm + wave * 32 + (lane >> 4) * 4;
    #pragma unroll
    for (int j = 0; j < 4; ++j) {
        const int col = (lane & 15) + j * 16;
        #pragma unroll
        for (int i = 0; i < 2; ++i)
            #pragma unroll
            for (int r = 0; r < 4; ++r)
                Cp[(size_t)(orow0 + i * 16 + r) * 64 + col] = acc[i][j][r];
    }
}

// ---------------------------------------------------------------------------
// xproj reduce: cols 0..31 -> dbc[m][32] (dt rows); cols 32..63 -> bct[m][32].
// ---------------------------------------------------------------------------
__global__ __launch_bounds__(256) void xproj_reduce_kernel(
    const float* __restrict__ part,
    float* __restrict__ dbc_f, float* __restrict__ dbc_b,
    float* __restrict__ bct_f, float* __restrict__ bct_b)
{
    const int dir = blockIdx.y;
    const int i = (blockIdx.x * 256 + threadIdx.x) * 4;
    const float* p = part + (size_t)dir * 4 * (MM * 64);
    float4 a = *(const float4*)(p + i);
    #pragma unroll
    for (int s = 1; s < 4; ++s) {
        float4 t = *(const float4*)(p + (size_t)s * (MM * 64) + i);
        a.x += t.x; a.y += t.y; a.z += t.z; a.w += t.w;
    }
    const int m = i >> 6, c = i & 63;
    if (c < 32) {
        float* dbc = dir ? dbc_b : dbc_f;
        *(float4*)(dbc + (size_t)m * 32 + c) = a;
    } else {
        float* bct = dir ? bct_b : bct_f;
        *(float4*)(bct + (size_t)m * 32 + (c - 32)) = a;
    }
}

// ---------------------------------------------------------------------------
// Batched fp32 GEMM w/ softplus + row bias (dt-proj), bf16 output.
// ---------------------------------------------------------------------------
__global__ __launch_bounds__(256) void dtproj_batch_kernel(
    int M, int N, int K,
    const float* __restrict__ A0, const float* __restrict__ A1, int lda,
    const float* __restrict__ B0, const float* __restrict__ B1, int ldb,
    const float* __restrict__ bias0, const float* __restrict__ bias1,
    unsigned short* __restrict__ C0, unsigned short* __restrict__ C1, int ldc)
{
    __shared__ float As[16][64];
    __shared__ float Bs[16][64];
    const int z = blockIdx.z;
    const float* A = z ? A1 : A0;
    const float* B = z ? B1 : B0;
    const float* biasR = z ? bias1 : bias0;
    unsigned short* C = z ? C1 : C0;
    const int tid = threadIdx.x;
    const int tx = tid & 15, ty = tid >> 4;
    const int bm = blockIdx.y * 64, bn = blockIdx.x * 64;
    const int lm = tid & 63;
    const int lk = (tid >> 6) * 4;
    const float* Arow = A + (size_t)(bm + lm) * lda + lk;
    const float* Brow = B + (size_t)(bn + lm) * ldb + lk;
    float acc[4][4] = {};
    for (int k0 = 0; k0 < K; k0 += 16) {
        float4 av = *(const float4*)(Arow + k0);
        float4 bv = *(const float4*)(Brow + k0);
        __syncthreads();
        As[lk+0][lm] = av.x; As[lk+1][lm] = av.y; As[lk+2][lm] = av.z; As[lk+3][lm] = av.w;
        Bs[lk+0][lm] = bv.x; Bs[lk+1][lm] = bv.y; Bs[lk+2][lm] = bv.z; Bs[lk+3][lm] = bv.w;
        __syncthreads();
        #pragma unroll
        for (int k = 0; k < 16; ++k) {
            float4 a = *(const float4*)(&As[k][ty*4]);
            float4 b = *(const float4*)(&Bs[k][tx*4]);
            float ar[4] = {a.x,a.y,a.z,a.w};
            float br[4] = {b.x,b.y,b.z,b.w};
            #pragma unroll
            for (int i = 0; i < 4; ++i)
                #pragma unroll
                for (int j = 0; j < 4; ++j)
                    acc[i][j] = fmaf(ar[i], br[j], acc[i][j]);
        }
    }
    const int row0 = bm + ty*4, col0 = bn + tx*4;
    #pragma unroll
    for (int i = 0; i < 4; ++i) {
        float br = biasR[row0 + i];
        ushort4v o;
        #pragma unroll
        for (int j = 0; j < 4; ++j) {
            float t = acc[i][j] + br;
            o[j] = f2bf(fmaxf(t, 0.f) + log1pf(__expf(-fabsf(t))));
        }
        *(ushort4v*)(C + (size_t)(row0 + i) * ldc + col0) = o;
    }
}

// ---------------------------------------------------------------------------
// Segmented casts: 5 pre-GEMM arrays -> one contiguous bf16 block.
// ---------------------------------------------------------------------------
__global__ __launch_bounds__(256) void cast_pre_kernel(
    const float* __restrict__ x, const float* __restrict__ w0,
    const float* __restrict__ w1, const float* __restrict__ xp0,
    const float* __restrict__ xp1, unsigned short* __restrict__ dst)
{
    int i = (blockIdx.x * 256 + threadIdx.x) * 8;
    const float* src; int off;
    if      (i < 1048576) { src = x;   off = 0; }
    else if (i < 2097152) { src = w0;  off = 1048576; }
    else if (i < 3145728) { src = w1;  off = 2097152; }
    else if (i < 3211264) { src = xp0; off = 3145728; }
    else                  { src = xp1; off = 3211264; }
    float4 a = *(const float4*)(src + i - off);
    float4 b = *(const float4*)(src + i - off + 4);
    ushort8v o;
    o[0] = f2bf(a.x); o[1] = f2bf(a.y); o[2] = f2bf(a.z); o[3] = f2bf(a.w);
    o[4] = f2bf(b.x); o[5] = f2bf(b.y); o[6] = f2bf(b.z); o[7] = f2bf(b.w);
    *(ushort8v*)(dst + i) = o;
}

// Segments: outW_f(524288) outW_b(524288) W1(1048576) W2(1048576)
__global__ __launch_bounds__(256) void cast_post_kernel(
    const float* __restrict__ w0, const float* __restrict__ w1,
    const float* __restrict__ w2, const float* __restrict__ w3,
    unsigned short* __restrict__ dst)
{
    int i = (blockIdx.x * 256 + threadIdx.x) * 8;
    const float* src; int off;
    if      (i < 524288)  { src = w0; off = 0; }
    else if (i < 1048576) { src = w1; off = 524288; }
    else if (i < 2097152) { src = w2; off = 1048576; }
    else                  { src = w3; off = 2097152; }
    float4 a = *(const float4*)(src + i - off);
    float4 b = *(const float4*)(src + i - off + 4);
    ushort8v o;
    o[0] = f2bf(a.x); o[1] = f2bf(a.y); o[2] = f2bf(a.z); o[3] = f2bf(a.w);
    o[4] = f2bf(b.x); o[5] = f2bf(b.y); o[6] = f2bf(b.z); o[7] = f2bf(b.w);
    *(ushort8v*)(dst + i) = o;
}

// ---------------------------------------------------------------------------
// Fused depthwise conv + bias + silu + transpose (bf16 x input):
// writes xm[m][d] and xmT[d][m] (bf16). 32x32 tile, blockIdx.z = dir.
// ---------------------------------------------------------------------------
__global__ __launch_bounds__(256) void conv_silu_tr_kernel(
    const unsigned short* __restrict__ x_f, const unsigned short* __restrict__ x_b,
    const float* __restrict__ Wf,  const float* __restrict__ Wb,
    const float* __restrict__ cbf, const float* __restrict__ cbb,
    unsigned short* __restrict__ of,  unsigned short* __restrict__ ob,
    unsigned short* __restrict__ otf, unsigned short* __restrict__ otb)
{
    __shared__ unsigned short t[32][34];
    const int dir = blockIdx.z;
    const unsigned short* xo = dir ? x_b : x_f;
    const float* convW = dir ? Wb : Wf;
    const float* convb = dir ? cbb : cbf;
    unsigned short* xm  = dir ? ob : of;
    unsigned short* xmT = dir ? otb : otf;
    const int m0 = blockIdx.x * 32, d0 = blockIdx.y * 32;
    const int tx = threadIdx.x & 31, ty = threadIdx.x >> 5;
    const int d = d0 + tx;
    float4 wv = *(const float4*)(convW + d * 4);
    float w[4] = {wv.x, wv.y, wv.z, wv.w};
    const float cb = convb[d];
    #pragma unroll
    for (int rr = 0; rr < 32; rr += 8) {
        int m = m0 + ty + rr;
        int b = m >> 10, l = m & (SEQ - 1);
        float acc = cb;
        #pragma unroll
        for (int j = 0; j < 4; ++j) {
            int p = dir ? (l + 3 - j) : (l - 3 + j);
            if (p >= 0 && p < SEQ)
                acc = fmaf(bf2f(xo[(size_t)(b * SEQ + p) * DINNER + d]), w[j], acc);
        }
        float sig = 1.f / (1.f + __expf(-acc));
        unsigned short v = f2bf(acc * sig);
        xm[(size_t)m * DINNER + d] = v;
        t[ty + rr][tx] = v;
    }
    __syncthreads();
    #pragma unroll
    for (int rr = 0; rr < 32; rr += 8)
        xmT[(size_t)(d0 + ty + rr) * MM + m0 + tx] = t[tx][ty + rr];
}

// ---------------------------------------------------------------------------
// Scan pass 1: local scan from zero state, 4 states per thread.
// ---------------------------------------------------------------------------
template<int DIR>
__device__ __forceinline__ void pass1_body(
    const unsigned short* __restrict__ deltaT, const unsigned short* __restrict__ xmT,
    const float* __restrict__ bct, const float* __restrict__ Alog,
    const float* __restrict__ Dv,
    unsigned short* __restrict__ y0T, float* __restrict__ cumT,
    float* __restrict__ Pout, float* __restrict__ Hout)
{
    const int tid = threadIdx.x;
    const int sq = tid & 3;
    const int dloc = tid >> 2;
    const int d = blockIdx.x * 64 + dloc;
    const int b = blockIdx.y / NCHUNK;
    const int c = blockIdx.y % NCHUNK;

    float4 Av = *(const float4*)(Alog + d * DSTATE + sq * 4);
    const float A0 = -__expf(Av.x), A1 = -__expf(Av.y);
    const float A2 = -__expf(Av.z), A3 = -__expf(Av.w);
    const float Dp = Dv[d];
    const unsigned short* dRow = deltaT + (size_t)d * MM + b * SEQ;
    const unsigned short* xRow = xmT + (size_t)d * MM + b * SEQ;
    const float* bcRow = bct + (size_t)(b * SEQ) * 32 + sq * 4;
    unsigned short* yRow = y0T + (size_t)d * MM + b * SEQ;
    float* uRow = cumT + (size_t)d * MM + b * SEQ;

    float h0 = 0.f, h1 = 0.f, h2 = 0.f, h3 = 0.f, sdl = 0.f;
    const int segBase = DIR ? (SEQ - CHUNK - c * CHUNK) : (c * CHUNK);
    for (int ii = 0; ii < CHUNK; ii += 8) {
        const int off = DIR ? (segBase + (CHUNK - 8) - ii) : (segBase + ii);
        ushort8v dl8 = *(const ushort8v*)(dRow + off);
        ushort8v x8  = *(const ushort8v*)(xRow + off);
        float yv[8], cu[8];
        #pragma unroll
        for (int u = 0; u < 8; ++u) {
            const int t = DIR ? (7 - u) : u;
            float4 Bv = *(const float4*)(bcRow + (size_t)(off + t) * 32);
            float4 Cv = *(const float4*)(bcRow + (size_t)(off + t) * 32 + 16);
            float dlv = bf2f(dl8[t]);
            float xv  = bf2f(x8[t]);
            sdl += dlv;
            float dx = dlv * xv;
            h0 = fmaf(__expf(dlv * A0), h0, dx * Bv.x);
            h1 = fmaf(__expf(dlv * A1), h1, dx * Bv.y);
            h2 = fmaf(__expf(dlv * A2), h2, dx * Bv.z);
            h3 = fmaf(__expf(dlv * A3), h3, dx * Bv.w);
            float part = h0 * Cv.x + h1 * Cv.y + h2 * Cv.z + h3 * Cv.w;
            part = quadsum4(part);
            yv[t] = fmaf(xv, Dp, part);
            cu[t] = sdl;
        }
        if (sq == 0) {
            ushort8v y8;
            #pragma unroll
            for (int u = 0; u < 8; ++u) y8[u] = f2bf(yv[u]);
            *(ushort8v*)(yRow + off) = y8;
            *(float4*)(uRow + off)     = (float4){cu[0], cu[1], cu[2], cu[3]};
            *(float4*)(uRow + off + 4) = (float4){cu[4], cu[5], cu[6], cu[7]};
        }
    }
    const size_t g4 = ((size_t)(DIR * BATCH + b) * DINNER + d) * DSTATE + sq * 4;
    *(float4*)(Pout + (size_t)c * GTOT + g4) =
        (float4){__expf(sdl * A0), __expf(sdl * A1), __expf(sdl * A2), __expf(sdl * A3)};
    *(float4*)(Hout + (size_t)c * GTOT + g4) = (float4){h0, h1, h2, h3};
}

__global__ __launch_bounds__(256) void scan_pass1_kernel(
    const unsigned short* __restrict__ dT_f, const unsigned short* __restrict__ dT_b,
    const unsigned short* __restrict__ xT_f, const unsigned short* __restrict__ xT_b,
    const float* __restrict__ bct_f, const float* __restrict__ bct_b,
    const float* __restrict__ Alog_f, const float* __restrict__ Alog_b,
    const float* __restrict__ D_f, const float* __restrict__ D_b,
    unsigned short* __restrict__ y0T_f, unsigned short* __restrict__ y0T_b,
    float* __restrict__ cumT_f, float* __restrict__ cumT_b,
    float* __restrict__ Pout, float* __restrict__ Hout)
{
    if (blockIdx.z == 0)
        pass1_body<0>(dT_f, xT_f, bct_f, Alog_f, D_f, y0T_f, cumT_f, Pout, Hout);
    else
        pass1_body<1>(dT_b, xT_b, bct_b, Alog_b, D_b, y0T_b, cumT_b, Pout, Hout);
}

// ---------------------------------------------------------------------------
// Phase 2: sequential combine over chunks (preloaded P/H).
// ---------------------------------------------------------------------------
__global__ __launch_bounds__(256) void scan_carry_kernel(
    const float* __restrict__ P, const float* __restrict__ H,
    float* __restrict__ carry)
{
    const int g = blockIdx.x * 256 + threadIdx.x;
    float p[NCHUNK], hh[NCHUNK];
    #pragma unroll
    for (int c = 0; c < NCHUNK; ++c) {
        p[c]  = P[(size_t)c * GTOT + g];
        hh[c] = H[(size_t)c * GTOT + g];
    }
    float h = 0.f;
    #pragma unroll
    for (int c = 0; c < NCHUNK; ++c) {
        carry[(size_t)c * GTOT + g] = h;
        h = fmaf(p[c], h, hh[c]);
    }
}

// ---------------------------------------------------------------------------
// Correction pass: y = y0 + sum_s C*carry*exp(A*cumdl); *= silu(z) (bf16 z);
// transpose -> ybf[m][d]. blockIdx.z = dir.
// ---------------------------------------------------------------------------
__global__ __launch_bounds__(256) void scan_correct_kernel(
    const unsigned short* __restrict__ y0T_f, const unsigned short* __restrict__ y0T_b,
    const float* __restrict__ cumT_f, const float* __restrict__ cumT_b,
    const float* __restrict__ bct_f, const float* __restrict__ bct_b,
    const float* __restrict__ Alog_f, const float* __restrict__ Alog_b,
    const float* __restrict__ carry,
    const unsigned short* __restrict__ z_f, const unsigned short* __restrict__ z_b,
    unsigned short* __restrict__ ybf_f, unsigned short* __restrict__ ybf_b)
{
    __shared__ float Cs[16][33];
    __shared__ float Asm[32][16];
    __shared__ float Cy[32][16];
    __shared__ float t[32][33];

    const int dir = blockIdx.z;
    const unsigned short* y0T = dir ? y0T_b : y0T_f;
    const float* cumT = dir ? cumT_b : cumT_f;
    const float* bct  = dir ? bct_b  : bct_f;
    const float* Alog = dir ? Alog_b : Alog_f;
    const unsigned short* zon = dir ? z_b : z_f;
    unsigned short* ybf = dir ? ybf_b : ybf_f;

    const int m0 = blockIdx.x * 32, d0 = blockIdx.y * 32;
    const int b = m0 >> 10;
    const int l0 = m0 & (SEQ - 1);
    const int c = dir ? ((SEQ - 1 - l0) >> 6) : (l0 >> 6);

    for (int idx = threadIdx.x; idx < 512; idx += 256) {
        int s1 = idx & 15, ml = idx >> 4;
        Cs[s1][ml] = bct[(size_t)(m0 + ml) * 32 + 16 + s1];
        int dl2 = idx >> 4, s2 = idx & 15;
        Asm[dl2][s2] = -__expf(Alog[(d0 + dl2) * DSTATE + s2]);
        Cy[dl2][s2] = carry[(size_t)c * GTOT
            + ((size_t)(dir * BATCH + b) * DINNER + d0 + dl2) * DSTATE + s2];
    }
    __syncthreads();

    const int tx = threadIdx.x & 31, ty = threadIdx.x >> 5;
    #pragma unroll
    for (int rr = 0; rr < 32; rr += 8) {
        const int dloc = ty + rr;
        const size_t base = (size_t)(d0 + dloc) * MM + m0 + tx;
        float u  = cumT[base];
        float y0 = bf2f(y0T[base]);
        float corr = 0.f;
        #pragma unroll
        for (int s = 0; s < DSTATE; ++s)
            corr = fmaf(Cs[s][tx] * Cy[dloc][s], __expf(Asm[dloc][s] * u), corr);
        t[dloc][tx] = y0 + corr;
    }
    __syncthreads();
    #pragma unroll
    for (int rr = 0; rr < 32; rr += 8) {
        int m = m0 + ty + rr, d = d0 + tx;
        float z = bf2f(zon[(size_t)m * DINNER + d]);
        float sig = 1.f / (1.f + __expf(-z));
        ybf[(size_t)m * DINNER + d] = f2bf(t[tx][ty + rr] * (z * sig));
    }
}

// ---------------------------------------------------------------------------
// Fused out-proj split-K2 reduce + dual LN -> bf16.
// part = [4][MM*DMODEL]: dir0 slices 0,1; dir1 slices 2,3.
// ---------------------------------------------------------------------------
__global__ __launch_bounds__(256) void ln_combine_fused_kernel(
    const float* __restrict__ xf, const float* __restrict__ part,
    const float* __restrict__ g1, const float* __restrict__ b1,
    const float* __restrict__ g2, const float* __restrict__ b2,
    unsigned short* __restrict__ out)
{
    const int m = blockIdx.x;
    const int tid = threadIdx.x;
    const size_t stride = (size_t)MM * DMODEL;
    const float* xr = xf + (size_t)m * DMODEL;
    const float* p = part + (size_t)m * DMODEL;
    float v1a = xr[tid]       + p[tid]              + p[stride + tid];
    float v1b = xr[tid + 256] + p[tid + 256]        + p[stride + tid + 256];
    float v2a = xr[tid]       + p[2*stride + tid]   + p[3*stride + tid];
    float v2b = xr[tid + 256] + p[2*stride + tid + 256] + p[3*stride + tid + 256];
    float s1 = v1a + v1b, q1 = v1a*v1a + v1b*v1b;
    float s2 = v2a + v2b, q2 = v2a*v2a + v2b*v2b;
    #pragma unroll
    for (int off = 32; off; off >>= 1) {
        s1 += __shfl_xor(s1, off); q1 += __shfl_xor(q1, off);
        s2 += __shfl_xor(s2, off); q2 += __shfl_xor(q2, off);
    }
    __shared__ float sm[4][4];
    const int w = tid >> 6;
    if ((tid & 63) == 0) { sm[w][0] = s1; sm[w][1] = q1; sm[w][2] = s2; sm[w][3] = q2; }
    __syncthreads();
    s1 = sm[0][0] + sm[1][0] + sm[2][0] + sm[3][0];
    q1 = sm[0][1] + sm[1][1] + sm[2][1] + sm[3][1];
    s2 = sm[0][2] + sm[1][2] + sm[2][2] + sm[3][2];
    q2 = sm[0][3] + sm[1][3] + sm[2][3] + sm[3][3];
    const float inv = 1.f / DMODEL;
    float mu1 = s1 * inv, mu2 = s2 * inv;
    float rs1 = rsqrtf(q1 * inv - mu1 * mu1 + 1e-5f);
    float rs2 = rsqrtf(q2 * inv - mu2 * mu2 + 1e-5f);
    unsigned short* orow = out + (size_t)m * DMODEL;
    orow[tid]       = f2bf((v1a - mu1) * rs1 * g1[tid]       + b1[tid]
                         + (v2a - mu2) * rs2 * g2[tid]       + b2[tid]);
    orow[tid + 256] = f2bf((v1b - mu1) * rs1 * g1[tid + 256] + b1[tid + 256]
                         + (v2b - mu2) * rs2 * g2[tid + 256] + b2[tid + 256]);
}

// ---------------------------------------------------------------------------
// Fused FF2 split-K4 reduce + bias + LN(2*ff).
// ---------------------------------------------------------------------------
__global__ __launch_bounds__(256) void ln_final_fused_kernel(
    const float* __restrict__ part, const float* __restrict__ bias,
    const float* __restrict__ g, const float* __restrict__ b,
    float* __restrict__ out)
{
    const int m = blockIdx.x;
    const int tid = threadIdx.x;
    const size_t stride = (size_t)MM * DMODEL;
    const float* p = part + (size_t)m * DMODEL;
    float fa = bias[tid]       + p[tid]       + p[stride + tid]
             + p[2*stride + tid]       + p[3*stride + tid];
    float fb = bias[tid + 256] + p[tid + 256] + p[stride + tid + 256]
             + p[2*stride + tid + 256] + p[3*stride + tid + 256];
    float va = 2.f * fa, vb = 2.f * fb;
    float s = va + vb, q = va*va + vb*vb;
    #pragma unroll
    for (int off = 32; off; off >>= 1) {
        s += __shfl_xor(s, off); q += __shfl_xor(q, off);
    }
    __shared__ float sm[4][2];
    const int w = tid >> 6;
    if ((tid & 63) == 0) { sm[w][0] = s; sm[w][1] = q; }
    __syncthreads();
    s = sm[0][0] + sm[1][0] + sm[2][0] + sm[3][0];
    q = sm[0][1] + sm[1][1] + sm[2][1] + sm[3][1];
    const float inv = 1.f / DMODEL;
    float mu = s * inv;
    float rs = rsqrtf(q * inv - mu * mu + 1e-5f);
    float* orow = out + (size_t)m * DMODEL;
    orow[tid]       = (va - mu) * rs * g[tid]       + b[tid];
    orow[tid + 256] = (vb - mu) * rs * g[tid + 256] + b[tid + 256];
}

// ---------------------------------------------------------------------------
extern "C" void kernel_launch(void* const* d_in, const int* in_sizes, int n_in,
                              void* d_out, int out_size, void* d_ws, size_t ws_size,
                              hipStream_t stream)
{
    const float* x         = (const float*)d_in[0];
    const float* fm_in_W   = (const float*)d_in[1];
    const float* fm_conv_W = (const float*)d_in[2];
    const float* fm_conv_b = (const float*)d_in[3];
    const float* fm_xproj_W= (const float*)d_in[4];
    const float* fm_dt_W   = (const float*)d_in[5];
    const float* fm_dt_b   = (const float*)d_in[6];
    const float* fm_A_log  = (const float*)d_in[7];
    const float* fm_D      = (const float*)d_in[8];
    const float* fm_out_W  = (const float*)d_in[9];
    const float* bm_in_W   = (const float*)d_in[10];
    const float* bm_conv_W = (const float*)d_in[11];
    const float* bm_conv_b = (const float*)d_in[12];
    const float* bm_xproj_W= (const float*)d_in[13];
    const float* bm_dt_W   = (const float*)d_in[14];
    const float* bm_dt_b   = (const float*)d_in[15];
    const float* bm_A_log  = (const float*)d_in[16];
    const float* bm_D      = (const float*)d_in[17];
    const float* bm_out_W  = (const float*)d_in[18];
    const float* ln1_g     = (const float*)d_in[19];
    const float* ln1_b     = (const float*)d_in[20];
    const float* ln2_g     = (const float*)d_in[21];
    const float* ln2_b     = (const float*)d_in[22];
    const float* ln3_g     = (const float*)d_in[23];
    const float* ln3_b     = (const float*)d_in[24];
    const float* ff_W1     = (const float*)d_in[25];
    const float* ff_b1     = (const float*)d_in[26];
    const float* ff_W2     = (const float*)d_in[27];
    const float* ff_b2     = (const float*)d_in[28];
    float* out = (float*)d_out;

    // ---- Workspace layout (floats; ~79 MB) ----
    float* ws = (float*)d_ws;
    size_t o = 0;
    unsigned short* xbf_f = (unsigned short*)(ws + o); o += (size_t)MM * DINNER / 2;
    unsigned short* xbf_b = (unsigned short*)(ws + o); o += (size_t)MM * DINNER / 2;
    unsigned short* zbf_f = (unsigned short*)(ws + o); o += (size_t)MM * DINNER / 2;
    unsigned short* zbf_b = (unsigned short*)(ws + o); o += (size_t)MM * DINNER / 2;
    unsigned short* xm_bf_f = (unsigned short*)(ws + o); o += (size_t)MM * DINNER / 2;
    unsigned short* xm_bf_b = (unsigned short*)(ws + o); o += (size_t)MM * DINNER / 2;
    unsigned short* xmT_f   = (unsigned short*)(ws + o); o += (size_t)MM * DINNER / 2;
    unsigned short* xmT_b   = (unsigned short*)(ws + o); o += (size_t)MM * DINNER / 2;
    unsigned short* deltaT_f= (unsigned short*)(ws + o); o += (size_t)MM * DINNER / 2;
    unsigned short* deltaT_b= (unsigned short*)(ws + o); o += (size_t)MM * DINNER / 2;
    float* dbc_f    = ws + o; o += (size_t)MM * 32;
    float* dbc_b    = ws + o; o += (size_t)MM * 32;
    float* bct_f    = ws + o; o += (size_t)MM * 32;
    float* bct_b    = ws + o; o += (size_t)MM * 32;
    unsigned short* y0T_f = (unsigned short*)(ws + o); o += (size_t)MM * DINNER / 2;
    unsigned short* y0T_b = (unsigned short*)(ws + o); o += (size_t)MM * DINNER / 2;
    float* scanP    = ws + o; o += (size_t)NCHUNK * (GTOT / 16) * 16;  // 1,048,576
    float* scanH    = ws + o; o += (size_t)NCHUNK * (GTOT / 16) * 16;
    float* scanCy   = ws + o; o += (size_t)NCHUNK * (GTOT / 16) * 16;
    float* gpart    = ws + o; o += (size_t)4 * MM * DMODEL;            // 4,194,304

    // ---- Overlays (sequenced reuse) ----
    // gpart timeline: xproj partials (1.05M) -> cumT (4.19M, by pass1)
    //   -> out-proj partials (4.19M) -> FF2 partials (4.19M).
    float* cumT_f = gpart;
    float* cumT_b = gpart + (size_t)MM * DINNER;
    unsigned short* xin_bf     = (unsigned short*)scanP;   // dead until pass1
    unsigned short* fm_inW_bf  = xin_bf + 1048576;
    unsigned short* bm_inW_bf  = fm_inW_bf + 1048576;
    unsigned short* fm_xpW_bf  = bm_inW_bf + 1048576;
    unsigned short* bm_xpW_bf  = fm_xpW_bf + 65536;
    unsigned short* ybf_f = (unsigned short*)scanP;        // P/H dead after carry
    unsigned short* ybf_b = (unsigned short*)scanH;
    unsigned short* fm_outW_bf = (unsigned short*)zbf_f;   // z dead after correct
    unsigned short* bm_outW_bf = fm_outW_bf + 524288;      // spans zbf_f..zbf_b
    unsigned short* W1_bf      = bm_outW_bf + 524288;
    unsigned short* W2_bf      = W1_bf + 1048576;
    unsigned short* outsum_bf  = (unsigned short*)xbf_f;   // x-half dead after conv
    unsigned short* h_bf = (unsigned short*)deltaT_f;      // deltaT dead after pass1

    // ---- 0. pre-GEMM casts ----
    cast_pre_kernel<<<3276800 / 2048, 256, 0, stream>>>(
        x, fm_in_W, bm_in_W, fm_xproj_W, bm_xproj_W, xin_bf);

    // ---- 1. in-proj GEMMs, bf16 split x/z outputs, both dirs (512 blocks) ----
    gemm_inproj_kernel<<<dim3(2048/128, MM/128, 2), 256, 0, stream>>>(
        xin_bf, fm_inW_bf, bm_inW_bf, xbf_f, zbf_f, xbf_b, zbf_b);

    // ---- 2. fused conv + silu + transpose -> xm[m][d], xmT[d][m] ----
    conv_silu_tr_kernel<<<dim3(MM/32, DINNER/32, 2), 256, 0, stream>>>(
        xbf_f, xbf_b, fm_conv_W, bm_conv_W, fm_conv_b, bm_conv_b,
        xm_bf_f, xm_bf_b, xmT_f, xmT_b);

    // ---- 3. x-proj: split-K x4, both dirs + reduce -> dbc[m][32], bct[m][32] ----
    xproj_splitk_kernel<<<dim3(MM/128, 8), 256, 0, stream>>>(
        xm_bf_f, xm_bf_b, fm_xpW_bf, bm_xpW_bf, gpart);
    xproj_reduce_kernel<<<dim3((MM*64)/1024, 2), 256, 0, stream>>>(
        gpart, dbc_f, dbc_b, bct_f, bct_b);

    // ---- 4. dt-proj, both dirs -> deltaT bf16 [d][m], softplus ----
    dtproj_batch_kernel<<<dim3(MM/64, DINNER/64, 2), 256, 0, stream>>>(
        DINNER, MM, DTRANK, fm_dt_W, bm_dt_W, DTRANK, dbc_f, dbc_b, 32,
        fm_dt_b, bm_dt_b, deltaT_f, deltaT_b, MM);

    // ---- 5. scan: pass1 (4 states/thread) + carry + parallel correction ----
    scan_pass1_kernel<<<dim3(DINNER/64, BATCH*NCHUNK, 2), 256, 0, stream>>>(
        deltaT_f, deltaT_b, xmT_f, xmT_b, bct_f, bct_b,
        fm_A_log, bm_A_log, fm_D, bm_D,
        y0T_f, y0T_b, cumT_f, cumT_b, scanP, scanH);
    scan_carry_kernel<<<GTOT/256, 256, 0, stream>>>(scanP, scanH, scanCy);
    scan_correct_kernel<<<dim3(MM/32, DINNER/32, 2), 256, 0, stream>>>(
        y0T_f, y0T_b, cumT_f, cumT_b, bct_f, bct_b, fm_A_log, bm_A_log,
        scanCy, zbf_f, zbf_b, ybf_f, ybf_b);

    // ---- 6. post weight casts (z region dead) ----
    cast_post_kernel<<<3145728 / 2048, 256, 0, stream>>>(
        fm_out_W, bm_out_W, ff_W1, ff_W2, fm_outW_bf);

    // ---- 7. out-proj: dirs x splitK2 (256 blocks) -> gpart ----
    gemm_mfma_splitk<2><<<dim3(DMODEL/128, MM/128, 4), 256, 0, stream>>>(
        MM, DMODEL, DINNER, ybf_f, ybf_b, DINNER, fm_outW_bf, bm_outW_bf, DINNER,
        gpart, DMODEL);

    // ---- 8. fused reduce (2/dir) + dual LN -> bf16 outsum ----
    ln_combine_fused_kernel<<<MM, 256, 0, stream>>>(
        x, gpart, ln1_g, ln1_b, ln2_g, ln2_b, outsum_bf);

    // ---- 9. FF1 direct (256 blocks), bf16 out ----
    gemm_mfma_batch<1,1><<<dim3(DFF/128, MM/128, 1), 256, 0, stream>>>(
        MM, DFF, DMODEL, outsum_bf, outsum_bf, DMODEL, W1_bf, W1_bf, DMODEL,
        ff_b1, h_bf, h_bf, DFF);

    // ---- 10. FF2: splitK4 (256 blocks) -> gpart ----
    gemm_mfma_splitk<4><<<dim3(DMODEL/128, MM/128, 4), 256, 0, stream>>>(
        MM, DMODEL, DFF, h_bf, h_bf, DFF, W2_bf, W2_bf, DFF, gpart, DMODEL);

    // ---- 11. fused reduce (4) + bias + final LN(2*ff) ----
    ln_final_fused_kernel<<<MM, 256, 0, stream>>>(
        gpart, ff_b2, ln3_g, ln3_b, out);
}

// Round 14
// 300.842 us; speedup vs baseline: 1.0243x; 1.0029x over previous
//
#include <hip/hip_runtime.h>
#include <hip/hip_bf16.h>
#include <math.h>

// Problem constants
#define MM 2048        // B*W flattened rows
#define BATCH 2
#define SEQ 1024
#define DMODEL 512
#define DINNER 1024
#define DSTATE 16
#define DTRANK 32
#define DFF 2048

// Chunked-scan constants
#define NCHUNK 16
#define CHUNK 64
#define GTOT 65536          // 2 dirs * BATCH * DINNER * DSTATE

typedef short bf16x8 __attribute__((ext_vector_type(8)));
typedef float floatx4 __attribute__((ext_vector_type(4)));
typedef unsigned short ushort8v __attribute__((ext_vector_type(8)));
typedef unsigned short ushort4v __attribute__((ext_vector_type(4)));

__device__ __forceinline__ unsigned short f2bf(float f) {
    union { float f; unsigned u; } v; v.f = f;
    unsigned r = v.u + 0x7FFF + ((v.u >> 16) & 1);
    return (unsigned short)(r >> 16);
}
__device__ __forceinline__ float bf2f(unsigned short u) {
    union { unsigned u; float f; } v; v.u = ((unsigned)u) << 16; return v.f;
}

// Sum across each 4-lane quad via DPP quad_perm adds (VALU-only).
__device__ __forceinline__ float quadsum4(float x) {
    union { float f; int i; } a, b;
    a.f = x;
    b.i = __builtin_amdgcn_update_dpp(0, a.i, 0xB1, 0xF, 0xF, false); a.f += b.f; // [1,0,3,2]
    b.i = __builtin_amdgcn_update_dpp(0, a.i, 0x4E, 0xF, 0xF, false); a.f += b.f; // [2,3,0,1]
    return a.f;
}

#define GLOAD_LDS16(gp, lp) __builtin_amdgcn_global_load_lds( \
    (const __attribute__((address_space(1))) unsigned int*)(gp), \
    (__attribute__((address_space(3))) unsigned int*)(lp), 16, 0, 0)

// NOTES (measured on this problem):
// - Single-buffered barrier-stage-barrier K-loops ONLY: LDS double-buffering
//   races (round-9 post-timing divergence; waitcnt tied to aliasing ds_reads).
// - BK=128 stages all four 32-k quarters into disjoint LDS before ONE barrier
//   (same single-buffer safety; 4 barrier drains for K=512 instead of 8).
// - Split-K beyond ~1 block/CU REGRESSES: fp32 partial traffic scales with
//   NSPLIT and cancels the occupancy gain (round 12). Optimum here:
//   out-proj splitK2/dir, FF2 splitK4, FF1 direct.

// ---------------------------------------------------------------------------
// Batched direct bf16 MFMA GEMM: C[z][M,N] = epi(A[z] @ B[z]^T + bias)
// 128x128 tile, BK=128. Conflict-free LDS. K % 128 == 0.
// ---------------------------------------------------------------------------
template<int EPI, int OUTBF16>
__global__ __launch_bounds__(256) void gemm_mfma_batch(
    int M, int N, int K,
    const unsigned short* __restrict__ A0, const unsigned short* __restrict__ A1, int lda,
    const unsigned short* __restrict__ B0, const unsigned short* __restrict__ B1, int ldb,
    const float* __restrict__ bias,
    void* __restrict__ C0, void* __restrict__ C1, int ldc)
{
    __shared__ unsigned short As[4][128 * 32];
    __shared__ unsigned short Bs[4][128 * 32];
    const int z = blockIdx.z;
    const unsigned short* A = z ? A1 : A0;
    const unsigned short* B = z ? B1 : B0;
    void* Cout = z ? C1 : C0;
    const int tid  = threadIdx.x;
    const int wave = tid >> 6;
    const int lane = tid & 63;
    const int bm = blockIdx.y * 128;
    const int bn = blockIdx.x * 128;

    const int strow = lane & 15;
    const int stkc  = lane >> 4;
    const int wr = wave >> 1, wc = wave & 1;
    const int frow = lane & 15;
    const int fkc  = lane >> 4;

    floatx4 acc[4][4];
    #pragma unroll
    for (int i = 0; i < 4; ++i)
        #pragma unroll
        for (int j = 0; j < 4; ++j)
            acc[i][j] = (floatx4){0.f, 0.f, 0.f, 0.f};

    for (int k0 = 0; k0 < K; k0 += 128) {
        __syncthreads();
        #pragma unroll
        for (int hh = 0; hh < 4; ++hh) {
            #pragma unroll
            for (int q = 0; q < 2; ++q) {
                int g = wave * 2 + q;
                GLOAD_LDS16(A + (size_t)(bm + g * 16 + strow) * lda + k0 + hh * 32 + stkc * 8,
                            As[hh] + g * 512);
            }
            #pragma unroll
            for (int q = 0; q < 2; ++q) {
                int g = wave * 2 + q;
                GLOAD_LDS16(B + (size_t)(bn + g * 16 + strow) * ldb + k0 + hh * 32 + stkc * 8,
                            Bs[hh] + g * 512);
            }
        }
        __syncthreads();

        #pragma unroll
        for (int hh = 0; hh < 4; ++hh) {
            bf16x8 af[4], bfr[4];
            #pragma unroll
            for (int i = 0; i < 4; ++i)
                af[i] = *(const bf16x8*)(As[hh] + (wr * 4 + i) * 512 + fkc * 128 + frow * 8);
            #pragma unroll
            for (int j = 0; j < 4; ++j)
                bfr[j] = *(const bf16x8*)(Bs[hh] + (wc * 4 + j) * 512 + fkc * 128 + frow * 8);
            #pragma unroll
            for (int i = 0; i < 4; ++i)
                #pragma unroll
                for (int j = 0; j < 4; ++j)
                    acc[i][j] = __builtin_amdgcn_mfma_f32_16x16x32_bf16(
                        af[i], bfr[j], acc[i][j], 0, 0, 0);
        }
    }

    const int orow0 = bm + wr * 64 + (lane >> 4) * 4;
    const int ocol0 = bn + wc * 64 + (lane & 15);
    #pragma unroll
    for (int j = 0; j < 4; ++j) {
        const int col = ocol0 + j * 16;
        const float bv = bias ? bias[col] : 0.f;
        #pragma unroll
        for (int i = 0; i < 4; ++i) {
            #pragma unroll
            for (int r = 0; r < 4; ++r) {
                int row = orow0 + i * 16 + r;
                float t = acc[i][j][r] + bv;
                if (EPI == 1) t = fmaxf(t, 0.f);
                if (OUTBF16)
                    ((unsigned short*)Cout)[(size_t)row * ldc + col] = f2bf(t);
                else
                    ((float*)Cout)[(size_t)row * ldc + col] = t;
            }
        }
    }
}

// ---------------------------------------------------------------------------
// In-proj GEMM (BK=128): writes bf16 x-half / z-half buffers (each [M][1024]).
// A shared across dirs; blockIdx.z = dir. M=MM, N=2048, K=512.
// ---------------------------------------------------------------------------
__global__ __launch_bounds__(256) void gemm_inproj_kernel(
    const unsigned short* __restrict__ A,
    const unsigned short* __restrict__ B0, const unsigned short* __restrict__ B1,
    unsigned short* __restrict__ Cx0, unsigned short* __restrict__ Cz0,
    unsigned short* __restrict__ Cx1, unsigned short* __restrict__ Cz1)
{
    __shared__ unsigned short As[4][128 * 32];
    __shared__ unsigned short Bs[4][128 * 32];
    const int z = blockIdx.z;
    const unsigned short* B = z ? B1 : B0;
    const int tid  = threadIdx.x;
    const int wave = tid >> 6;
    const int lane = tid & 63;
    const int bm = blockIdx.y * 128;
    const int bn = blockIdx.x * 128;

    const int strow = lane & 15;
    const int stkc  = lane >> 4;
    const int wr = wave >> 1, wc = wave & 1;
    const int frow = lane & 15;
    const int fkc  = lane >> 4;

    floatx4 acc[4][4];
    #pragma unroll
    for (int i = 0; i < 4; ++i)
        #pragma unroll
        for (int j = 0; j < 4; ++j)
            acc[i][j] = (floatx4){0.f, 0.f, 0.f, 0.f};

    for (int k0 = 0; k0 < DMODEL; k0 += 128) {
        __syncthreads();
        #pragma unroll
        for (int hh = 0; hh < 4; ++hh) {
            #pragma unroll
            for (int q = 0; q < 2; ++q) {
                int g = wave * 2 + q;
                GLOAD_LDS16(A + (size_t)(bm + g * 16 + strow) * DMODEL + k0 + hh * 32 + stkc * 8,
                            As[hh] + g * 512);
            }
            #pragma unroll
            for (int q = 0; q < 2; ++q) {
                int g = wave * 2 + q;
                GLOAD_LDS16(B + (size_t)(bn + g * 16 + strow) * DMODEL + k0 + hh * 32 + stkc * 8,
                            Bs[hh] + g * 512);
            }
        }
        __syncthreads();

        #pragma unroll
        for (int hh = 0; hh < 4; ++hh) {
            bf16x8 af[4], bfr[4];
            #pragma unroll
            for (int i = 0; i < 4; ++i)
                af[i] = *(const bf16x8*)(As[hh] + (wr * 4 + i) * 512 + fkc * 128 + frow * 8);
            #pragma unroll
            for (int j = 0; j < 4; ++j)
                bfr[j] = *(const bf16x8*)(Bs[hh] + (wc * 4 + j) * 512 + fkc * 128 + frow * 8);
            #pragma unroll
            for (int i = 0; i < 4; ++i)
                #pragma unroll
                for (int j = 0; j < 4; ++j)
                    acc[i][j] = __builtin_amdgcn_mfma_f32_16x16x32_bf16(
                        af[i], bfr[j], acc[i][j], 0, 0, 0);
        }
    }

    const int zh = bn >= DINNER;
    unsigned short* C = z ? (zh ? Cz1 : Cx1) : (zh ? Cz0 : Cx0);
    const int cb = zh ? DINNER : 0;
    const int orow0 = bm + wr * 64 + (lane >> 4) * 4;
    const int ocol0 = bn + wc * 64 + (lane & 15) - cb;
    #pragma unroll
    for (int j = 0; j < 4; ++j) {
        const int col = ocol0 + j * 16;
        #pragma unroll
        for (int i = 0; i < 4; ++i)
            #pragma unroll
            for (int r = 0; r < 4; ++r)
                C[(size_t)(orow0 + i * 16 + r) * DINNER + col] = f2bf(acc[i][j][r]);
    }
}

// ---------------------------------------------------------------------------
// Split-K batched MFMA GEMM (BK=128) -> fp32 partials part[z][M*ldc].
// z = dir*NSPLIT + sp. (K/NSPLIT) % 128 == 0.
// ---------------------------------------------------------------------------
template<int NSPLIT>
__global__ __launch_bounds__(256) void gemm_mfma_splitk(
    int M, int N, int K,
    const unsigned short* __restrict__ A0, const unsigned short* __restrict__ A1, int lda,
    const unsigned short* __restrict__ B0, const unsigned short* __restrict__ B1, int ldb,
    float* __restrict__ part, int ldc)
{
    __shared__ unsigned short As[4][128 * 32];
    __shared__ unsigned short Bs[4][128 * 32];
    const int z = blockIdx.z;
    const int dir = z / NSPLIT, sp = z % NSPLIT;
    const unsigned short* A = dir ? A1 : A0;
    const unsigned short* B = dir ? B1 : B0;
    float* Cp = part + (size_t)z * M * ldc;
    const int kbeg = sp * (K / NSPLIT);
    const int kend = kbeg + (K / NSPLIT);
    const int tid  = threadIdx.x;
    const int wave = tid >> 6;
    const int lane = tid & 63;
    const int bm = blockIdx.y * 128;
    const int bn = blockIdx.x * 128;

    const int strow = lane & 15;
    const int stkc  = lane >> 4;
    const int wr = wave >> 1, wc = wave & 1;
    const int frow = lane & 15;
    const int fkc  = lane >> 4;

    floatx4 acc[4][4];
    #pragma unroll
    for (int i = 0; i < 4; ++i)
        #pragma unroll
        for (int j = 0; j < 4; ++j)
            acc[i][j] = (floatx4){0.f, 0.f, 0.f, 0.f};

    for (int k0 = kbeg; k0 < kend; k0 += 128) {
        __syncthreads();
        #pragma unroll
        for (int hh = 0; hh < 4; ++hh) {
            #pragma unroll
            for (int q = 0; q < 2; ++q) {
                int g = wave * 2 + q;
                GLOAD_LDS16(A + (size_t)(bm + g * 16 + strow) * lda + k0 + hh * 32 + stkc * 8,
                            As[hh] + g * 512);
            }
            #pragma unroll
            for (int q = 0; q < 2; ++q) {
                int g = wave * 2 + q;
                GLOAD_LDS16(B + (size_t)(bn + g * 16 + strow) * ldb + k0 + hh * 32 + stkc * 8,
                            Bs[hh] + g * 512);
            }
        }
        __syncthreads();

        #pragma unroll
        for (int hh = 0; hh < 4; ++hh) {
            bf16x8 af[4], bfr[4];
            #pragma unroll
            for (int i = 0; i < 4; ++i)
                af[i] = *(const bf16x8*)(As[hh] + (wr * 4 + i) * 512 + fkc * 128 + frow * 8);
            #pragma unroll
            for (int j = 0; j < 4; ++j)
                bfr[j] = *(const bf16x8*)(Bs[hh] + (wc * 4 + j) * 512 + fkc * 128 + frow * 8);
            #pragma unroll
            for (int i = 0; i < 4; ++i)
                #pragma unroll
                for (int j = 0; j < 4; ++j)
                    acc[i][j] = __builtin_amdgcn_mfma_f32_16x16x32_bf16(
                        af[i], bfr[j], acc[i][j], 0, 0, 0);
        }
    }

    const int orow0 = bm + wr * 64 + (lane >> 4) * 4;
    const int ocol0 = bn + wc * 64 + (lane & 15);
    #pragma unroll
    for (int j = 0; j < 4; ++j) {
        const int col = ocol0 + j * 16;
        #pragma unroll
        for (int i = 0; i < 4; ++i)
            #pragma unroll
            for (int r = 0; r < 4; ++r)
                Cp[(size_t)(orow0 + i * 16 + r) * ldc + col] = acc[i][j][r];
    }
}

// ---------------------------------------------------------------------------
// xproj split-K MFMA (BK=128): tile 128(m) x 64(n), K slice 256.
// blockIdx.y = dir*4 + sp.
// ---------------------------------------------------------------------------
__global__ __launch_bounds__(256) void xproj_splitk_kernel(
    const unsigned short* __restrict__ A_f, const unsigned short* __restrict__ A_b,
    const unsigned short* __restrict__ Wf,  const unsigned short* __restrict__ Wb,
    float* __restrict__ part)
{
    __shared__ unsigned short As[4][128 * 32];
    __shared__ unsigned short Bs[4][64 * 32];
    const int tid = threadIdx.x, wave = tid >> 6, lane = tid & 63;
    const int bm = blockIdx.x * 128;
    const int dir = blockIdx.y >> 2, sp = blockIdx.y & 3;
    const unsigned short* A = dir ? A_b : A_f;
    const unsigned short* W = dir ? Wb  : Wf;
    float* Cp = part + (size_t)blockIdx.y * MM * 64;
    const int kbeg = sp * 256, kend = kbeg + 256;

    const int strow = lane & 15;
    const int stkc  = lane >> 4;
    const int frow = lane & 15;
    const int fkc  = lane >> 4;

    floatx4 acc[2][4];
    #pragma unroll
    for (int i = 0; i < 2; ++i)
        #pragma unroll
        for (int j = 0; j < 4; ++j)
            acc[i][j] = (floatx4){0.f, 0.f, 0.f, 0.f};

    for (int k0 = kbeg; k0 < kend; k0 += 128) {
        __syncthreads();
        #pragma unroll
        for (int hh = 0; hh < 4; ++hh) {
            #pragma unroll
            for (int q = 0; q < 2; ++q) {
                int g = wave * 2 + q;
                GLOAD_LDS16(A + (size_t)(bm + g * 16 + strow) * DINNER + k0 + hh * 32 + stkc * 8,
                            As[hh] + g * 512);
            }
            GLOAD_LDS16(W + (size_t)(wave * 16 + strow) * DINNER + k0 + hh * 32 + stkc * 8,
                        Bs[hh] + wave * 512);
        }
        __syncthreads();

        #pragma unroll
        for (int hh = 0; hh < 4; ++hh) {
            bf16x8 af[2], bfr[4];
            #pragma unroll
            for (int i = 0; i < 2; ++i)
                af[i] = *(const bf16x8*)(As[hh] + (wave * 2 + i) * 512 + fkc * 128 + frow * 8);
            #pragma unroll
            for (int j = 0; j < 4; ++j)
                bfr[j] = *(const bf16x8*)(Bs[hh] + j * 512 + fkc * 128 + frow * 8);
            #pragma unroll
            for (int i = 0; i < 2; ++i)
                #pragma unroll
                for (int j = 0; j < 4; ++j)
                    acc[i][j] = __builtin_amdgcn_mfma_f32_16x16x32_bf16(
                        af[i], bfr[j], acc[i][j], 0, 0, 0);
        }
    }

    const int orow0 = bm + wave * 32 + (lane >> 4) * 4;
    #pragma unroll
    for (int j = 0; j < 4; ++j) {
        const int col = (lane & 15) + j * 16;
        #pragma unroll
        for (int i = 0; i < 2; ++i)
            #pragma unroll
            for (int r = 0; r < 4; ++r)
                Cp[(size_t)(orow0 + i * 16 + r) * 64 + col] = acc[i][j][r];
    }
}

// ---------------------------------------------------------------------------
// xproj reduce: cols 0..31 -> dbc[m][32] (dt rows); cols 32..63 -> bct[m][32].
// ---------------------------------------------------------------------------
__global__ __launch_bounds__(256) void xproj_reduce_kernel(
    const float* __restrict__ part,
    float* __restrict__ dbc_f, float* __restrict__ dbc_b,
    float* __restrict__ bct_f, float* __restrict__ bct_b)
{
    const int dir = blockIdx.y;
    const int i = (blockIdx.x * 256 + threadIdx.x) * 4;
    const float* p = part + (size_t)dir * 4 * (MM * 64);
    float4 a = *(const float4*)(p + i);
    #pragma unroll
    for (int s = 1; s < 4; ++s) {
        float4 t = *(const float4*)(p + (size_t)s * (MM * 64) + i);
        a.x += t.x; a.y += t.y; a.z += t.z; a.w += t.w;
    }
    const int m = i >> 6, c = i & 63;
    if (c < 32) {
        float* dbc = dir ? dbc_b : dbc_f;
        *(float4*)(dbc + (size_t)m * 32 + c) = a;
    } else {
        float* bct = dir ? bct_b : bct_f;
        *(float4*)(bct + (size_t)m * 32 + (c - 32)) = a;
    }
}

// ---------------------------------------------------------------------------
// Batched fp32 GEMM w/ softplus + row bias (dt-proj), bf16 output.
// ---------------------------------------------------------------------------
__global__ __launch_bounds__(256) void dtproj_batch_kernel(
    int M, int N, int K,
    const float* __restrict__ A0, const float* __restrict__ A1, int lda,
    const float* __restrict__ B0, const float* __restrict__ B1, int ldb,
    const float* __restrict__ bias0, const float* __restrict__ bias1,
    unsigned short* __restrict__ C0, unsigned short* __restrict__ C1, int ldc)
{
    __shared__ float As[16][64];
    __shared__ float Bs[16][64];
    const int z = blockIdx.z;
    const float* A = z ? A1 : A0;
    const float* B = z ? B1 : B0;
    const float* biasR = z ? bias1 : bias0;
    unsigned short* C = z ? C1 : C0;
    const int tid = threadIdx.x;
    const int tx = tid & 15, ty = tid >> 4;
    const int bm = blockIdx.y * 64, bn = blockIdx.x * 64;
    const int lm = tid & 63;
    const int lk = (tid >> 6) * 4;
    const float* Arow = A + (size_t)(bm + lm) * lda + lk;
    const float* Brow = B + (size_t)(bn + lm) * ldb + lk;
    float acc[4][4] = {};
    for (int k0 = 0; k0 < K; k0 += 16) {
        float4 av = *(const float4*)(Arow + k0);
        float4 bv = *(const float4*)(Brow + k0);
        __syncthreads();
        As[lk+0][lm] = av.x; As[lk+1][lm] = av.y; As[lk+2][lm] = av.z; As[lk+3][lm] = av.w;
        Bs[lk+0][lm] = bv.x; Bs[lk+1][lm] = bv.y; Bs[lk+2][lm] = bv.z; Bs[lk+3][lm] = bv.w;
        __syncthreads();
        #pragma unroll
        for (int k = 0; k < 16; ++k) {
            float4 a = *(const float4*)(&As[k][ty*4]);
            float4 b = *(const float4*)(&Bs[k][tx*4]);
            float ar[4] = {a.x,a.y,a.z,a.w};
            float br[4] = {b.x,b.y,b.z,b.w};
            #pragma unroll
            for (int i = 0; i < 4; ++i)
                #pragma unroll
                for (int j = 0; j < 4; ++j)
                    acc[i][j] = fmaf(ar[i], br[j], acc[i][j]);
        }
    }
    const int row0 = bm + ty*4, col0 = bn + tx*4;
    #pragma unroll
    for (int i = 0; i < 4; ++i) {
        float br = biasR[row0 + i];
        ushort4v o;
        #pragma unroll
        for (int j = 0; j < 4; ++j) {
            float t = acc[i][j] + br;
            o[j] = f2bf(fmaxf(t, 0.f) + log1pf(__expf(-fabsf(t))));
        }
        *(ushort4v*)(C + (size_t)(row0 + i) * ldc + col0) = o;
    }
}

// ---------------------------------------------------------------------------
// Mega-cast: all 9 fp32->bf16 conversions in one dispatch.
// Segments (ushort idx): x 0..1048576, inW_f ..2097152, inW_b ..3145728,
// xpW_f ..3211264, xpW_b ..3276800, outW_f ..3801088, outW_b ..4325376,
// W1 ..5373952, W2 ..6422528.
// ---------------------------------------------------------------------------
__global__ __launch_bounds__(256) void cast_all_kernel(
    const float* __restrict__ x,
    const float* __restrict__ inw0, const float* __restrict__ inw1,
    const float* __restrict__ xp0,  const float* __restrict__ xp1,
    const float* __restrict__ ow0,  const float* __restrict__ ow1,
    const float* __restrict__ w1,   const float* __restrict__ w2,
    unsigned short* __restrict__ dst)
{
    int i = (blockIdx.x * 256 + threadIdx.x) * 8;
    const float* src; int off;
    if      (i < 1048576) { src = x;    off = 0; }
    else if (i < 2097152) { src = inw0; off = 1048576; }
    else if (i < 3145728) { src = inw1; off = 2097152; }
    else if (i < 3211264) { src = xp0;  off = 3145728; }
    else if (i < 3276800) { src = xp1;  off = 3211264; }
    else if (i < 3801088) { src = ow0;  off = 3276800; }
    else if (i < 4325376) { src = ow1;  off = 3801088; }
    else if (i < 5373952) { src = w1;   off = 4325376; }
    else                  { src = w2;   off = 5373952; }
    float4 a = *(const float4*)(src + i - off);
    float4 b = *(const float4*)(src + i - off + 4);
    ushort8v o;
    o[0] = f2bf(a.x); o[1] = f2bf(a.y); o[2] = f2bf(a.z); o[3] = f2bf(a.w);
    o[4] = f2bf(b.x); o[5] = f2bf(b.y); o[6] = f2bf(b.z); o[7] = f2bf(b.w);
    *(ushort8v*)(dst + i) = o;
}

// ---------------------------------------------------------------------------
// Fused depthwise conv + bias + silu + transpose (bf16 x input):
// writes xm[m][d] and xmT[d][m] (bf16). 32x32 tile, blockIdx.z = dir.
// ---------------------------------------------------------------------------
__global__ __launch_bounds__(256) void conv_silu_tr_kernel(
    const unsigned short* __restrict__ x_f, const unsigned short* __restrict__ x_b,
    const float* __restrict__ Wf,  const float* __restrict__ Wb,
    const float* __restrict__ cbf, const float* __restrict__ cbb,
    unsigned short* __restrict__ of,  unsigned short* __restrict__ ob,
    unsigned short* __restrict__ otf, unsigned short* __restrict__ otb)
{
    __shared__ unsigned short t[32][34];
    const int dir = blockIdx.z;
    const unsigned short* xo = dir ? x_b : x_f;
    const float* convW = dir ? Wb : Wf;
    const float* convb = dir ? cbb : cbf;
    unsigned short* xm  = dir ? ob : of;
    unsigned short* xmT = dir ? otb : otf;
    const int m0 = blockIdx.x * 32, d0 = blockIdx.y * 32;
    const int tx = threadIdx.x & 31, ty = threadIdx.x >> 5;
    const int d = d0 + tx;
    float4 wv = *(const float4*)(convW + d * 4);
    float w[4] = {wv.x, wv.y, wv.z, wv.w};
    const float cb = convb[d];
    #pragma unroll
    for (int rr = 0; rr < 32; rr += 8) {
        int m = m0 + ty + rr;
        int b = m >> 10, l = m & (SEQ - 1);
        float acc = cb;
        #pragma unroll
        for (int j = 0; j < 4; ++j) {
            int p = dir ? (l + 3 - j) : (l - 3 + j);
            if (p >= 0 && p < SEQ)
                acc = fmaf(bf2f(xo[(size_t)(b * SEQ + p) * DINNER + d]), w[j], acc);
        }
        float sig = 1.f / (1.f + __expf(-acc));
        unsigned short v = f2bf(acc * sig);
        xm[(size_t)m * DINNER + d] = v;
        t[ty + rr][tx] = v;
    }
    __syncthreads();
    #pragma unroll
    for (int rr = 0; rr < 32; rr += 8)
        xmT[(size_t)(d0 + ty + rr) * MM + m0 + tx] = t[tx][ty + rr];
}

// ---------------------------------------------------------------------------
// Scan pass 1: local scan from zero state, 4 states per thread.
// ---------------------------------------------------------------------------
template<int DIR>
__device__ __forceinline__ void pass1_body(
    const unsigned short* __restrict__ deltaT, const unsigned short* __restrict__ xmT,
    const float* __restrict__ bct, const float* __restrict__ Alog,
    const float* __restrict__ Dv,
    unsigned short* __restrict__ y0T, float* __restrict__ cumT,
    float* __restrict__ Pout, float* __restrict__ Hout)
{
    const int tid = threadIdx.x;
    const int sq = tid & 3;
    const int dloc = tid >> 2;
    const int d = blockIdx.x * 64 + dloc;
    const int b = blockIdx.y / NCHUNK;
    const int c = blockIdx.y % NCHUNK;

    float4 Av = *(const float4*)(Alog + d * DSTATE + sq * 4);
    const float A0 = -__expf(Av.x), A1 = -__expf(Av.y);
    const float A2 = -__expf(Av.z), A3 = -__expf(Av.w);
    const float Dp = Dv[d];
    const unsigned short* dRow = deltaT + (size_t)d * MM + b * SEQ;
    const unsigned short* xRow = xmT + (size_t)d * MM + b * SEQ;
    const float* bcRow = bct + (size_t)(b * SEQ) * 32 + sq * 4;
    unsigned short* yRow = y0T + (size_t)d * MM + b * SEQ;
    float* uRow = cumT + (size_t)d * MM + b * SEQ;

    float h0 = 0.f, h1 = 0.f, h2 = 0.f, h3 = 0.f, sdl = 0.f;
    const int segBase = DIR ? (SEQ - CHUNK - c * CHUNK) : (c * CHUNK);
    for (int ii = 0; ii < CHUNK; ii += 8) {
        const int off = DIR ? (segBase + (CHUNK - 8) - ii) : (segBase + ii);
        ushort8v dl8 = *(const ushort8v*)(dRow + off);
        ushort8v x8  = *(const ushort8v*)(xRow + off);
        float yv[8], cu[8];
        #pragma unroll
        for (int u = 0; u < 8; ++u) {
            const int t = DIR ? (7 - u) : u;
            float4 Bv = *(const float4*)(bcRow + (size_t)(off + t) * 32);
            float4 Cv = *(const float4*)(bcRow + (size_t)(off + t) * 32 + 16);
            float dlv = bf2f(dl8[t]);
            float xv  = bf2f(x8[t]);
            sdl += dlv;
            float dx = dlv * xv;
            h0 = fmaf(__expf(dlv * A0), h0, dx * Bv.x);
            h1 = fmaf(__expf(dlv * A1), h1, dx * Bv.y);
            h2 = fmaf(__expf(dlv * A2), h2, dx * Bv.z);
            h3 = fmaf(__expf(dlv * A3), h3, dx * Bv.w);
            float part = h0 * Cv.x + h1 * Cv.y + h2 * Cv.z + h3 * Cv.w;
            part = quadsum4(part);
            yv[t] = fmaf(xv, Dp, part);
            cu[t] = sdl;
        }
        if (sq == 0) {
            ushort8v y8;
            #pragma unroll
            for (int u = 0; u < 8; ++u) y8[u] = f2bf(yv[u]);
            *(ushort8v*)(yRow + off) = y8;
            *(float4*)(uRow + off)     = (float4){cu[0], cu[1], cu[2], cu[3]};
            *(float4*)(uRow + off + 4) = (float4){cu[4], cu[5], cu[6], cu[7]};
        }
    }
    const size_t g4 = ((size_t)(DIR * BATCH + b) * DINNER + d) * DSTATE + sq * 4;
    *(float4*)(Pout + (size_t)c * GTOT + g4) =
        (float4){__expf(sdl * A0), __expf(sdl * A1), __expf(sdl * A2), __expf(sdl * A3)};
    *(float4*)(Hout + (size_t)c * GTOT + g4) = (float4){h0, h1, h2, h3};
}

__global__ __launch_bounds__(256) void scan_pass1_kernel(
    const unsigned short* __restrict__ dT_f, const unsigned short* __restrict__ dT_b,
    const unsigned short* __restrict__ xT_f, const unsigned short* __restrict__ xT_b,
    const float* __restrict__ bct_f, const float* __restrict__ bct_b,
    const float* __restrict__ Alog_f, const float* __restrict__ Alog_b,
    const float* __restrict__ D_f, const float* __restrict__ D_b,
    unsigned short* __restrict__ y0T_f, unsigned short* __restrict__ y0T_b,
    float* __restrict__ cumT_f, float* __restrict__ cumT_b,
    float* __restrict__ Pout, float* __restrict__ Hout)
{
    if (blockIdx.z == 0)
        pass1_body<0>(dT_f, xT_f, bct_f, Alog_f, D_f, y0T_f, cumT_f, Pout, Hout);
    else
        pass1_body<1>(dT_b, xT_b, bct_b, Alog_b, D_b, y0T_b, cumT_b, Pout, Hout);
}

// ---------------------------------------------------------------------------
// Phase 2: sequential combine over chunks (preloaded P/H).
// ---------------------------------------------------------------------------
__global__ __launch_bounds__(256) void scan_carry_kernel(
    const float* __restrict__ P, const float* __restrict__ H,
    float* __restrict__ carry)
{
    const int g = blockIdx.x * 256 + threadIdx.x;
    float p[NCHUNK], hh[NCHUNK];
    #pragma unroll
    for (int c = 0; c < NCHUNK; ++c) {
        p[c]  = P[(size_t)c * GTOT + g];
        hh[c] = H[(size_t)c * GTOT + g];
    }
    float h = 0.f;
    #pragma unroll
    for (int c = 0; c < NCHUNK; ++c) {
        carry[(size_t)c * GTOT + g] = h;
        h = fmaf(p[c], h, hh[c]);
    }
}

// ---------------------------------------------------------------------------
// Correction pass: y = y0 + sum_s C*carry*exp(A*cumdl); *= silu(z) (bf16 z);
// transpose -> ybf[m][d]. blockIdx.z = dir.
// ---------------------------------------------------------------------------
__global__ __launch_bounds__(256) void scan_correct_kernel(
    const unsigned short* __restrict__ y0T_f, const unsigned short* __restrict__ y0T_b,
    const float* __restrict__ cumT_f, const float* __restrict__ cumT_b,
    const float* __restrict__ bct_f, const float* __restrict__ bct_b,
    const float* __restrict__ Alog_f, const float* __restrict__ Alog_b,
    const float* __restrict__ carry,
    const unsigned short* __restrict__ z_f, const unsigned short* __restrict__ z_b,
    unsigned short* __restrict__ ybf_f, unsigned short* __restrict__ ybf_b)
{
    __shared__ float Cs[16][33];
    __shared__ float Asm[32][16];
    __shared__ float Cy[32][16];
    __shared__ float t[32][33];

    const int dir = blockIdx.z;
    const unsigned short* y0T = dir ? y0T_b : y0T_f;
    const float* cumT = dir ? cumT_b : cumT_f;
    const float* bct  = dir ? bct_b  : bct_f;
    const float* Alog = dir ? Alog_b : Alog_f;
    const unsigned short* zon = dir ? z_b : z_f;
    unsigned short* ybf = dir ? ybf_b : ybf_f;

    const int m0 = blockIdx.x * 32, d0 = blockIdx.y * 32;
    const int b = m0 >> 10;
    const int l0 = m0 & (SEQ - 1);
    const int c = dir ? ((SEQ - 1 - l0) >> 6) : (l0 >> 6);

    for (int idx = threadIdx.x; idx < 512; idx += 256) {
        int s1 = idx & 15, ml = idx >> 4;
        Cs[s1][ml] = bct[(size_t)(m0 + ml) * 32 + 16 + s1];
        int dl2 = idx >> 4, s2 = idx & 15;
        Asm[dl2][s2] = -__expf(Alog[(d0 + dl2) * DSTATE + s2]);
        Cy[dl2][s2] = carry[(size_t)c * GTOT
            + ((size_t)(dir * BATCH + b) * DINNER + d0 + dl2) * DSTATE + s2];
    }
    __syncthreads();

    const int tx = threadIdx.x & 31, ty = threadIdx.x >> 5;
    #pragma unroll
    for (int rr = 0; rr < 32; rr += 8) {
        const int dloc = ty + rr;
        const size_t base = (size_t)(d0 + dloc) * MM + m0 + tx;
        float u  = cumT[base];
        float y0 = bf2f(y0T[base]);
        float corr = 0.f;
        #pragma unroll
        for (int s = 0; s < DSTATE; ++s)
            corr = fmaf(Cs[s][tx] * Cy[dloc][s], __expf(Asm[dloc][s] * u), corr);
        t[dloc][tx] = y0 + corr;
    }
    __syncthreads();
    #pragma unroll
    for (int rr = 0; rr < 32; rr += 8) {
        int m = m0 + ty + rr, d = d0 + tx;
        float z = bf2f(zon[(size_t)m * DINNER + d]);
        float sig = 1.f / (1.f + __expf(-z));
        ybf[(size_t)m * DINNER + d] = f2bf(t[tx][ty + rr] * (z * sig));
    }
}

// ---------------------------------------------------------------------------
// Fused out-proj split-K2 reduce + dual LN -> bf16.
// part = [4][MM*DMODEL]: dir0 slices 0,1; dir1 slices 2,3.
// ---------------------------------------------------------------------------
__global__ __launch_bounds__(256) void ln_combine_fused_kernel(
    const float* __restrict__ xf, const float* __restrict__ part,
    const float* __restrict__ g1, const float* __restrict__ b1,
    const float* __restrict__ g2, const float* __restrict__ b2,
    unsigned short* __restrict__ out)
{
    const int m = blockIdx.x;
    const int tid = threadIdx.x;
    const size_t stride = (size_t)MM * DMODEL;
    const float* xr = xf + (size_t)m * DMODEL;
    const float* p = part + (size_t)m * DMODEL;
    float v1a = xr[tid]       + p[tid]              + p[stride + tid];
    float v1b = xr[tid + 256] + p[tid + 256]        + p[stride + tid + 256];
    float v2a = xr[tid]       + p[2*stride + tid]   + p[3*stride + tid];
    float v2b = xr[tid + 256] + p[2*stride + tid + 256] + p[3*stride + tid + 256];
    float s1 = v1a + v1b, q1 = v1a*v1a + v1b*v1b;
    float s2 = v2a + v2b, q2 = v2a*v2a + v2b*v2b;
    #pragma unroll
    for (int off = 32; off; off >>= 1) {
        s1 += __shfl_xor(s1, off); q1 += __shfl_xor(q1, off);
        s2 += __shfl_xor(s2, off); q2 += __shfl_xor(q2, off);
    }
    __shared__ float sm[4][4];
    const int w = tid >> 6;
    if ((tid & 63) == 0) { sm[w][0] = s1; sm[w][1] = q1; sm[w][2] = s2; sm[w][3] = q2; }
    __syncthreads();
    s1 = sm[0][0] + sm[1][0] + sm[2][0] + sm[3][0];
    q1 = sm[0][1] + sm[1][1] + sm[2][1] + sm[3][1];
    s2 = sm[0][2] + sm[1][2] + sm[2][2] + sm[3][2];
    q2 = sm[0][3] + sm[1][3] + sm[2][3] + sm[3][3];
    const float inv = 1.f / DMODEL;
    float mu1 = s1 * inv, mu2 = s2 * inv;
    float rs1 = rsqrtf(q1 * inv - mu1 * mu1 + 1e-5f);
    float rs2 = rsqrtf(q2 * inv - mu2 * mu2 + 1e-5f);
    unsigned short* orow = out + (size_t)m * DMODEL;
    orow[tid]       = f2bf((v1a - mu1) * rs1 * g1[tid]       + b1[tid]
                         + (v2a - mu2) * rs2 * g2[tid]       + b2[tid]);
    orow[tid + 256] = f2bf((v1b - mu1) * rs1 * g1[tid + 256] + b1[tid + 256]
                         + (v2b - mu2) * rs2 * g2[tid + 256] + b2[tid + 256]);
}

// ---------------------------------------------------------------------------
// Fused FF2 split-K4 reduce + bias + LN(2*ff).
// ---------------------------------------------------------------------------
__global__ __launch_bounds__(256) void ln_final_fused_kernel(
    const float* __restrict__ part, const float* __restrict__ bias,
    const float* __restrict__ g, const float* __restrict__ b,
    float* __restrict__ out)
{
    const int m = blockIdx.x;
    const int tid = threadIdx.x;
    const size_t stride = (size_t)MM * DMODEL;
    const float* p = part + (size_t)m * DMODEL;
    float fa = bias[tid]       + p[tid]       + p[stride + tid]
             + p[2*stride + tid]       + p[3*stride + tid];
    float fb = bias[tid + 256] + p[tid + 256] + p[stride + tid + 256]
             + p[2*stride + tid + 256] + p[3*stride + tid + 256];
    float va = 2.f * fa, vb = 2.f * fb;
    float s = va + vb, q = va*va + vb*vb;
    #pragma unroll
    for (int off = 32; off; off >>= 1) {
        s += __shfl_xor(s, off); q += __shfl_xor(q, off);
    }
    __shared__ float sm[4][2];
    const int w = tid >> 6;
    if ((tid & 63) == 0) { sm[w][0] = s; sm[w][1] = q; }
    __syncthreads();
    s = sm[0][0] + sm[1][0] + sm[2][0] + sm[3][0];
    q = sm[0][1] + sm[1][1] + sm[2][1] + sm[3][1];
    const float inv = 1.f / DMODEL;
    float mu = s * inv;
    float rs = rsqrtf(q * inv - mu * mu + 1e-5f);
    float* orow = out + (size_t)m * DMODEL;
    orow[tid]       = (va - mu) * rs * g[tid]       + b[tid];
    orow[tid + 256] = (vb - mu) * rs * g[tid + 256] + b[tid + 256];
}

// ---------------------------------------------------------------------------
extern "C" void kernel_launch(void* const* d_in, const int* in_sizes, int n_in,
                              void* d_out, int out_size, void* d_ws, size_t ws_size,
                              hipStream_t stream)
{
    const float* x         = (const float*)d_in[0];
    const float* fm_in_W   = (const float*)d_in[1];
    const float* fm_conv_W = (const float*)d_in[2];
    const float* fm_conv_b = (const float*)d_in[3];
    const float* fm_xproj_W= (const float*)d_in[4];
    const float* fm_dt_W   = (const float*)d_in[5];
    const float* fm_dt_b   = (const float*)d_in[6];
    const float* fm_A_log  = (const float*)d_in[7];
    const float* fm_D      = (const float*)d_in[8];
    const float* fm_out_W  = (const float*)d_in[9];
    const float* bm_in_W   = (const float*)d_in[10];
    const float* bm_conv_W = (const float*)d_in[11];
    const float* bm_conv_b = (const float*)d_in[12];
    const float* bm_xproj_W= (const float*)d_in[13];
    const float* bm_dt_W   = (const float*)d_in[14];
    const float* bm_dt_b   = (const float*)d_in[15];
    const float* bm_A_log  = (const float*)d_in[16];
    const float* bm_D      = (const float*)d_in[17];
    const float* bm_out_W  = (const float*)d_in[18];
    const float* ln1_g     = (const float*)d_in[19];
    const float* ln1_b     = (const float*)d_in[20];
    const float* ln2_g     = (const float*)d_in[21];
    const float* ln2_b     = (const float*)d_in[22];
    const float* ln3_g     = (const float*)d_in[23];
    const float* ln3_b     = (const float*)d_in[24];
    const float* ff_W1     = (const float*)d_in[25];
    const float* ff_b1     = (const float*)d_in[26];
    const float* ff_W2     = (const float*)d_in[27];
    const float* ff_b2     = (const float*)d_in[28];
    float* out = (float*)d_out;

    // ---- Workspace layout (floats; ~94 MB) ----
    float* ws = (float*)d_ws;
    size_t o = 0;
    unsigned short* wcast = (unsigned short*)(ws + o); o += 3276800;   // 6.55M bf16
    unsigned short* xbf_f = (unsigned short*)(ws + o); o += (size_t)MM * DINNER / 2;
    unsigned short* xbf_b = (unsigned short*)(ws + o); o += (size_t)MM * DINNER / 2;
    unsigned short* zbf_f = (unsigned short*)(ws + o); o += (size_t)MM * DINNER / 2;
    unsigned short* zbf_b = (unsigned short*)(ws + o); o += (size_t)MM * DINNER / 2;
    unsigned short* xm_bf_f = (unsigned short*)(ws + o); o += (size_t)MM * DINNER / 2;
    unsigned short* xm_bf_b = (unsigned short*)(ws + o); o += (size_t)MM * DINNER / 2;
    unsigned short* xmT_f   = (unsigned short*)(ws + o); o += (size_t)MM * DINNER / 2;
    unsigned short* xmT_b   = (unsigned short*)(ws + o); o += (size_t)MM * DINNER / 2;
    unsigned short* deltaT_f= (unsigned short*)(ws + o); o += (size_t)MM * DINNER / 2;
    unsigned short* deltaT_b= (unsigned short*)(ws + o); o += (size_t)MM * DINNER / 2;
    float* dbc_f    = ws + o; o += (size_t)MM * 32;
    float* dbc_b    = ws + o; o += (size_t)MM * 32;
    float* bct_f    = ws + o; o += (size_t)MM * 32;
    float* bct_b    = ws + o; o += (size_t)MM * 32;
    unsigned short* y0T_f = (unsigned short*)(ws + o); o += (size_t)MM * DINNER / 2;
    unsigned short* y0T_b = (unsigned short*)(ws + o); o += (size_t)MM * DINNER / 2;
    float* scanP    = ws + o; o += (size_t)NCHUNK * (GTOT / 16) * 16;  // 1,048,576
    float* scanH    = ws + o; o += (size_t)NCHUNK * (GTOT / 16) * 16;
    float* scanCy   = ws + o; o += (size_t)NCHUNK * (GTOT / 16) * 16;
    float* gpart    = ws + o; o += (size_t)4 * MM * DMODEL;            // 4,194,304

    // bf16 cast region layout (ushort offsets within wcast)
    unsigned short* xin_bf     = wcast;
    unsigned short* fm_inW_bf  = wcast + 1048576;
    unsigned short* bm_inW_bf  = wcast + 2097152;
    unsigned short* fm_xpW_bf  = wcast + 3145728;
    unsigned short* bm_xpW_bf  = wcast + 3211264;
    unsigned short* fm_outW_bf = wcast + 3276800;
    unsigned short* bm_outW_bf = wcast + 3801088;
    unsigned short* W1_bf      = wcast + 4325376;
    unsigned short* W2_bf      = wcast + 5373952;

    // ---- Overlays (sequenced reuse) ----
    // gpart timeline: xproj partials (1.05M) -> cumT (4.19M, by pass1)
    //   -> out-proj partials (4.19M) -> FF2 partials (4.19M).
    float* cumT_f = gpart;
    float* cumT_b = gpart + (size_t)MM * DINNER;
    unsigned short* ybf_f = (unsigned short*)scanP;        // P/H dead after carry
    unsigned short* ybf_b = (unsigned short*)scanH;
    unsigned short* outsum_bf = (unsigned short*)xbf_f;    // x-half dead after conv
    unsigned short* h_bf = (unsigned short*)deltaT_f;      // deltaT dead after pass1

    // ---- 0. mega-cast (1 dispatch, all fp32->bf16) ----
    cast_all_kernel<<<3136, 256, 0, stream>>>(
        x, fm_in_W, bm_in_W, fm_xproj_W, bm_xproj_W,
        fm_out_W, bm_out_W, ff_W1, ff_W2, wcast);

    // ---- 1. in-proj GEMMs, bf16 split x/z outputs, both dirs (512 blocks) ----
    gemm_inproj_kernel<<<dim3(2048/128, MM/128, 2), 256, 0, stream>>>(
        xin_bf, fm_inW_bf, bm_inW_bf, xbf_f, zbf_f, xbf_b, zbf_b);

    // ---- 2. fused conv + silu + transpose -> xm[m][d], xmT[d][m] ----
    conv_silu_tr_kernel<<<dim3(MM/32, DINNER/32, 2), 256, 0, stream>>>(
        xbf_f, xbf_b, fm_conv_W, bm_conv_W, fm_conv_b, bm_conv_b,
        xm_bf_f, xm_bf_b, xmT_f, xmT_b);

    // ---- 3. x-proj: split-K x4, both dirs + reduce -> dbc[m][32], bct[m][32] ----
    xproj_splitk_kernel<<<dim3(MM/128, 8), 256, 0, stream>>>(
        xm_bf_f, xm_bf_b, fm_xpW_bf, bm_xpW_bf, gpart);
    xproj_reduce_kernel<<<dim3((MM*64)/1024, 2), 256, 0, stream>>>(
        gpart, dbc_f, dbc_b, bct_f, bct_b);

    // ---- 4. dt-proj, both dirs -> deltaT bf16 [d][m], softplus ----
    dtproj_batch_kernel<<<dim3(MM/64, DINNER/64, 2), 256, 0, stream>>>(
        DINNER, MM, DTRANK, fm_dt_W, bm_dt_W, DTRANK, dbc_f, dbc_b, 32,
        fm_dt_b, bm_dt_b, deltaT_f, deltaT_b, MM);

    // ---- 5. scan: pass1 (4 states/thread) + carry + parallel correction ----
    scan_pass1_kernel<<<dim3(DINNER/64, BATCH*NCHUNK, 2), 256, 0, stream>>>(
        deltaT_f, deltaT_b, xmT_f, xmT_b, bct_f, bct_b,
        fm_A_log, bm_A_log, fm_D, bm_D,
        y0T_f, y0T_b, cumT_f, cumT_b, scanP, scanH);
    scan_carry_kernel<<<GTOT/256, 256, 0, stream>>>(scanP, scanH, scanCy);
    scan_correct_kernel<<<dim3(MM/32, DINNER/32, 2), 256, 0, stream>>>(
        y0T_f, y0T_b, cumT_f, cumT_b, bct_f, bct_b, fm_A_log, bm_A_log,
        scanCy, zbf_f, zbf_b, ybf_f, ybf_b);

    // ---- 6. out-proj: dirs x splitK2 (256 blocks) -> gpart ----
    gemm_mfma_splitk<2><<<dim3(DMODEL/128, MM/128, 4), 256, 0, stream>>>(
        MM, DMODEL, DINNER, ybf_f, ybf_b, DINNER, fm_outW_bf, bm_outW_bf, DINNER,
        gpart, DMODEL);

    // ---- 7. fused reduce (2/dir) + dual LN -> bf16 outsum ----
    ln_combine_fused_kernel<<<MM, 256, 0, stream>>>(
        x, gpart, ln1_g, ln1_b, ln2_g, ln2_b, outsum_bf);

    // ---- 8. FF1 direct (256 blocks), bf16 out ----
    gemm_mfma_batch<1,1><<<dim3(DFF/128, MM/128, 1), 256, 0, stream>>>(
        MM, DFF, DMODEL, outsum_bf, outsum_bf, DMODEL, W1_bf, W1_bf, DMODEL,
        ff_b1, h_bf, h_bf, DFF);

    // ---- 9. FF2: splitK4 (256 blocks) -> gpart ----
    gemm_mfma_splitk<4><<<dim3(DMODEL/128, MM/128, 4), 256, 0, stream>>>(
        MM, DMODEL, DFF, h_bf, h_bf, DFF, W2_bf, W2_bf, DFF, gpart, DMODEL);

    // ---- 10. fused reduce (4) + bias + final LN(2*ff) ----
    ln_final_fused_kernel<<<MM, 256, 0, stream>>>(
        gpart, ff_b2, ln3_g, ln3_b, out);
}